// Round 11
// baseline (168.375 us; speedup 1.0000x reference)
//
#include <hip/hip_runtime.h>

#define BATCH 64
#define RNN   512
#define VOCAB 50000
#define OOV   50
#define VEXT  50050
#define NSRC  512
#define NOB2  391   // out2 ocol-parts

typedef short bf16x8 __attribute__((ext_vector_type(8)));
typedef float f32x4  __attribute__((ext_vector_type(4)));

__device__ __forceinline__ float sigmoidf_(float x) { return 1.f / (1.f + __expf(-x)); }

__device__ __forceinline__ float gru_one(float ir, float iz, float inn,
                                         float hr, float hz, float hn, float h)
{
    const float r = sigmoidf_(ir + hr);
    const float z = sigmoidf_(iz + hz);
    const float n = tanhf(inn + r * hn);
    return (1.f - z) * n + z * h;
}

__device__ __forceinline__ short f2bf(float x) {
    unsigned u = __builtin_bit_cast(unsigned, x);
    unsigned r = (u + 0x7FFFu + ((u >> 16) & 1u)) >> 16;
    return (short)r;
}
__device__ __forceinline__ float bf2f(short s) {
    unsigned u = ((unsigned)(unsigned short)s) << 16;
    return __builtin_bit_cast(float, u);
}

// ---------------- small GEMM: C[b,o] = sum_k A[b,k] * W(o,k) (+bias) ----------------
// WT=true : W is (O,K) row-major (PyTorch Linear layout, x@W.T)
// grid = (O/32, 4 /*k-split*/, nz). Writes PARTIALS: C + blockIdx.y*64*O.
// asum: A is 4 partial slices [4][64][K] summed while staging.
// FAILED-EXPERIMENT LOG (do not retry): register-prefetch (R4: s_t absmax 1.9e-2);
// per-block __threadfence completion fusion (R7: 3.8x regression, L2-writeback
// serialization); scatter-into-output accumulate (R8: replay-idempotence);
// consumer-side o1p f32 staging in out2 (R9: 391 blocks x 512KB re-read, +35us).
template<bool WT>
__global__ __launch_bounds__(256) void k_gemm_small(
    const float* __restrict__ A0, const float* __restrict__ W0,
    const float* __restrict__ bias0, float* __restrict__ C0, int asum0,
    const float* __restrict__ A1, const float* __restrict__ W1,
    const float* __restrict__ bias1, float* __restrict__ C1, int asum1,
    int K, int O)
{
    const float* A = A0; const float* W = W0; const float* bias = bias0;
    float* C = C0; int asum = asum0;
    if (blockIdx.z == 1) { A = A1; W = W1; bias = bias1; C = C1; asum = asum1; }

    __shared__ float As[32 * 64];   // [k][b]
    __shared__ float Ws[32 * 32];   // [k][o]
    const int t  = threadIdx.x;
    const int tx = t & 15, ty = t >> 4;
    const int o0 = blockIdx.x * 32;
    const int kchunk = K >> 2;
    const int kbeg = blockIdx.y * kchunk;
    const int kend = kbeg + kchunk;
    float acc[4][2] = {};
    const int ab  = t >> 2;         // 0..63
    const int akq = (t & 3) * 4;    // 0,4,8,12

    for (int k0 = kbeg; k0 < kend; k0 += 32) {
        {
            const float* Ap = &A[(size_t)ab * K + k0 + akq];
            float4 v0 = *(const float4*)Ap;
            float4 v1 = *(const float4*)(Ap + 16);
            if (asum) {
                #pragma unroll
                for (int s = 1; s < 4; s++) {
                    const float* Aps = Ap + (size_t)s * 64 * K;
                    float4 w0 = *(const float4*)Aps;
                    float4 w1 = *(const float4*)(Aps + 16);
                    v0.x += w0.x; v0.y += w0.y; v0.z += w0.z; v0.w += w0.w;
                    v1.x += w1.x; v1.y += w1.y; v1.z += w1.z; v1.w += w1.w;
                }
            }
            As[(akq+0)*64+ab]=v0.x; As[(akq+1)*64+ab]=v0.y; As[(akq+2)*64+ab]=v0.z; As[(akq+3)*64+ab]=v0.w;
            As[(akq+16)*64+ab]=v1.x; As[(akq+17)*64+ab]=v1.y; As[(akq+18)*64+ab]=v1.z; As[(akq+19)*64+ab]=v1.w;
        }
        if (WT) {
            const int o  = t >> 3;          // 0..31
            const int kq = (t & 7) * 4;     // 0..28
            float4 v = *(const float4*)&W[(size_t)(o0 + o) * K + k0 + kq];
            Ws[(kq+0)*32+o]=v.x; Ws[(kq+1)*32+o]=v.y; Ws[(kq+2)*32+o]=v.z; Ws[(kq+3)*32+o]=v.w;
        } else {
            const int kk = t >> 3;          // 0..31
            const int oq = (t & 7) * 4;
            *(float4*)&Ws[kk*32 + oq] = *(const float4*)&W[(size_t)(k0 + kk) * O + o0 + oq];
        }
        __syncthreads();
        #pragma unroll
        for (int kk = 0; kk < 32; kk++) {
            float4 a4 = *(const float4*)&As[kk*64 + ty*4];
            float2 w2 = *(const float2*)&Ws[kk*32 + tx*2];
            acc[0][0] = fmaf(a4.x, w2.x, acc[0][0]); acc[0][1] = fmaf(a4.x, w2.y, acc[0][1]);
            acc[1][0] = fmaf(a4.y, w2.x, acc[1][0]); acc[1][1] = fmaf(a4.y, w2.y, acc[1][1]);
            acc[2][0] = fmaf(a4.z, w2.x, acc[2][0]); acc[2][1] = fmaf(a4.z, w2.y, acc[2][1]);
            acc[3][0] = fmaf(a4.w, w2.x, acc[3][0]); acc[3][1] = fmaf(a4.w, w2.y, acc[3][1]);
        }
        __syncthreads();
    }
    const int o = o0 + tx*2;
    float b0v = 0.f, b1v = 0.f;
    if (bias && blockIdx.y == 0) { b0v = bias[o]; b1v = bias[o+1]; }
    float* Cp = C + (size_t)blockIdx.y * 64 * O;
    #pragma unroll
    for (int j = 0; j < 4; j++) {
        const int bb = ty*4 + j;
        Cp[(size_t)bb*O + o]     = acc[j][0] + b0v;
        Cp[(size_t)bb*O + o + 1] = acc[j][1] + b1v;
    }
}

// ---------------- GEMM with fused x0 gather: x = [c_t_1, emb[y]] @ W.T + b ----------------
// K=1024, O=512, W (O,K) row-major, grid (16,4), partials to C + y*64*512.
__global__ __launch_bounds__(256) void k_gemm_x0(
    const int* __restrict__ yidx, const float* __restrict__ ct1, const float* __restrict__ emb,
    const float* __restrict__ W, const float* __restrict__ bias, float* __restrict__ C)
{
    __shared__ float As[32 * 64];
    __shared__ float Ws[32 * 32];
    const int t  = threadIdx.x;
    const int tx = t & 15, ty = t >> 4;
    const int o0 = blockIdx.x * 32;
    const int kbeg = blockIdx.y * 256;
    const int kend = kbeg + 256;
    float acc[4][2] = {};
    const int ab  = t >> 2;
    const int akq = (t & 3) * 4;
    const int erow = yidx[ab];

    for (int k0 = kbeg; k0 < kend; k0 += 32) {
        {
            // tile [k0,k0+32) lies entirely in one half (512 % 32 == 0)
            const float* src = (k0 < 512) ? (ct1 + (size_t)ab * 512 + k0)
                                          : (emb + (size_t)erow * 512 + (k0 - 512));
            float4 v0 = *(const float4*)(src + akq);
            float4 v1 = *(const float4*)(src + akq + 16);
            As[(akq+0)*64+ab]=v0.x; As[(akq+1)*64+ab]=v0.y; As[(akq+2)*64+ab]=v0.z; As[(akq+3)*64+ab]=v0.w;
            As[(akq+16)*64+ab]=v1.x; As[(akq+17)*64+ab]=v1.y; As[(akq+18)*64+ab]=v1.z; As[(akq+19)*64+ab]=v1.w;
        }
        {
            const int o  = t >> 3;
            const int kq = (t & 7) * 4;
            float4 v = *(const float4*)&W[(size_t)(o0 + o) * 1024 + k0 + kq];
            Ws[(kq+0)*32+o]=v.x; Ws[(kq+1)*32+o]=v.y; Ws[(kq+2)*32+o]=v.z; Ws[(kq+3)*32+o]=v.w;
        }
        __syncthreads();
        #pragma unroll
        for (int kk = 0; kk < 32; kk++) {
            float4 a4 = *(const float4*)&As[kk*64 + ty*4];
            float2 w2 = *(const float2*)&Ws[kk*32 + tx*2];
            acc[0][0] = fmaf(a4.x, w2.x, acc[0][0]); acc[0][1] = fmaf(a4.x, w2.y, acc[0][1]);
            acc[1][0] = fmaf(a4.y, w2.x, acc[1][0]); acc[1][1] = fmaf(a4.y, w2.y, acc[1][1]);
            acc[2][0] = fmaf(a4.z, w2.x, acc[2][0]); acc[2][1] = fmaf(a4.z, w2.y, acc[2][1]);
            acc[3][0] = fmaf(a4.w, w2.x, acc[3][0]); acc[3][1] = fmaf(a4.w, w2.y, acc[3][1]);
        }
        __syncthreads();
    }
    const int o = o0 + tx*2;
    float b0v = 0.f, b1v = 0.f;
    if (blockIdx.y == 0) { b0v = bias[o]; b1v = bias[o+1]; }
    float* Cp = C + (size_t)blockIdx.y * 64 * 512;
    #pragma unroll
    for (int j = 0; j < 4; j++) {
        const int bb = ty*4 + j;
        Cp[(size_t)bb*512 + o]     = acc[j][0] + b0v;
        Cp[(size_t)bb*512 + o + 1] = acc[j][1] + b1v;
    }
}

// ---------------- GEMM with fused GRU: u = GRU(gi,gh,hprev) @ W ----------------
// gi/gh are 4 k-split partial slices [4][64][1536]. W (K,O)=(512,512) row-major (x@W).
// grid (16, KS), 256 thr. Partials to C + y*64*512. Block x==0 also writes h (+cat).
template<int KS>
__global__ __launch_bounds__(256) void k_gemm_gru(
    const float* __restrict__ gi, const float* __restrict__ gh,
    const float* __restrict__ hprev, const float* __restrict__ W,
    float* __restrict__ C, float* __restrict__ hout, float* __restrict__ cat_out)
{
    __shared__ float As[32 * 64];
    __shared__ float Ws[32 * 32];
    const int t  = threadIdx.x;
    const int tx = t & 15, ty = t >> 4;
    const int o0 = blockIdx.x * 32;
    const int kchunk = 512 / KS;
    const int kbeg = blockIdx.y * kchunk;
    const int kend = kbeg + kchunk;
    float acc[4][2] = {};
    const int ab  = t >> 2;
    const int akq = (t & 3) * 4;

    for (int k0 = kbeg; k0 < kend; k0 += 32) {
        #pragma unroll
        for (int half = 0; half < 2; half++) {
            const int d = k0 + akq + half * 16;
            float irv[4] = {0,0,0,0}, izv[4] = {0,0,0,0}, inv_[4] = {0,0,0,0};
            float hrv[4] = {0,0,0,0}, hzv[4] = {0,0,0,0}, hnv[4] = {0,0,0,0};
            #pragma unroll
            for (int s = 0; s < 4; s++) {
                const float* gp = gi + (size_t)s * BATCH * 1536 + (size_t)ab * 1536 + d;
                const float* hp = gh + (size_t)s * BATCH * 1536 + (size_t)ab * 1536 + d;
                float4 a0 = *(const float4*)(gp);
                float4 a1 = *(const float4*)(gp + 512);
                float4 a2 = *(const float4*)(gp + 1024);
                float4 b0 = *(const float4*)(hp);
                float4 b1 = *(const float4*)(hp + 512);
                float4 b2 = *(const float4*)(hp + 1024);
                irv[0]+=a0.x; irv[1]+=a0.y; irv[2]+=a0.z; irv[3]+=a0.w;
                izv[0]+=a1.x; izv[1]+=a1.y; izv[2]+=a1.z; izv[3]+=a1.w;
                inv_[0]+=a2.x; inv_[1]+=a2.y; inv_[2]+=a2.z; inv_[3]+=a2.w;
                hrv[0]+=b0.x; hrv[1]+=b0.y; hrv[2]+=b0.z; hrv[3]+=b0.w;
                hzv[0]+=b1.x; hzv[1]+=b1.y; hzv[2]+=b1.z; hzv[3]+=b1.w;
                hnv[0]+=b2.x; hnv[1]+=b2.y; hnv[2]+=b2.z; hnv[3]+=b2.w;
            }
            const float4 hq = *(const float4*)(hprev + (size_t)ab * 512 + d);
            float o0v = gru_one(irv[0], izv[0], inv_[0], hrv[0], hzv[0], hnv[0], hq.x);
            float o1v = gru_one(irv[1], izv[1], inv_[1], hrv[1], hzv[1], hnv[1], hq.y);
            float o2v = gru_one(irv[2], izv[2], inv_[2], hrv[2], hzv[2], hnv[2], hq.z);
            float o3v = gru_one(irv[3], izv[3], inv_[3], hrv[3], hzv[3], hnv[3], hq.w);
            const int kk = akq + half * 16;
            As[(kk+0)*64+ab] = o0v; As[(kk+1)*64+ab] = o1v;
            As[(kk+2)*64+ab] = o2v; As[(kk+3)*64+ab] = o3v;
            if (blockIdx.x == 0) {
                float4 ov = make_float4(o0v, o1v, o2v, o3v);
                *(float4*)&hout[(size_t)ab * 512 + d] = ov;
                if (cat_out) *(float4*)&cat_out[(size_t)ab * 1024 + d] = ov;
            }
        }
        {
            const int kk = t >> 3;
            const int oq = (t & 7) * 4;
            *(float4*)&Ws[kk*32 + oq] = *(const float4*)&W[(size_t)(k0 + kk) * 512 + o0 + oq];
        }
        __syncthreads();
        #pragma unroll
        for (int kk = 0; kk < 32; kk++) {
            float4 a4 = *(const float4*)&As[kk*64 + ty*4];
            float2 w2 = *(const float2*)&Ws[kk*32 + tx*2];
            acc[0][0] = fmaf(a4.x, w2.x, acc[0][0]); acc[0][1] = fmaf(a4.x, w2.y, acc[0][1]);
            acc[1][0] = fmaf(a4.y, w2.x, acc[1][0]); acc[1][1] = fmaf(a4.y, w2.y, acc[1][1]);
            acc[2][0] = fmaf(a4.z, w2.x, acc[2][0]); acc[2][1] = fmaf(a4.z, w2.y, acc[2][1]);
            acc[3][0] = fmaf(a4.w, w2.x, acc[3][0]); acc[3][1] = fmaf(a4.w, w2.y, acc[3][1]);
        }
        __syncthreads();
    }
    const int o = o0 + tx*2;
    float* Cp = C + (size_t)blockIdx.y * 64 * 512;
    #pragma unroll
    for (int j = 0; j < 4; j++) {
        const int bb = ty*4 + j;
        Cp[(size_t)bb*512 + o]     = acc[j][0];
        Cp[(size_t)bb*512 + o + 1] = acc[j][1];
    }
}

// ---------------- fused attention pass ----------------
__global__ __launch_bounds__(256) void k_attn_pass(
    const float* __restrict__ KV, const float* __restrict__ Upart,
    const float* __restrict__ mask, float* __restrict__ en, float* __restrict__ part)
{
    const int b = blockIdx.y;
    const int chunk = blockIdx.x;
    const int t = threadIdx.x;
    const int lane = t & 63;
    const int wv = t >> 6;
    const float* KVb = KV + (size_t)b * NSRC * RNN;

    const int r0 = chunk * 32 + wv * 8;

    float4 x[8][2];
    float mk[8];
    #pragma unroll
    for (int i = 0; i < 8; i++) {
        const float* rp = KVb + (size_t)(r0 + i) * RNN + lane * 8;
        x[i][0] = *(const float4*)rp;
        x[i][1] = *(const float4*)(rp + 4);
    }
    #pragma unroll
    for (int i = 0; i < 8; i++) mk[i] = mask[(size_t)b * NSRC + r0 + i];

    float4 u0, u1;
    {
        const float* up = Upart + (size_t)b * RNN + lane * 8;
        u0 = *(const float4*)up; u1 = *(const float4*)(up + 4);
        #pragma unroll
        for (int s = 1; s < 8; s++) {
            const float* ups = up + (size_t)s * BATCH * RNN;
            float4 a = *(const float4*)ups; float4 c = *(const float4*)(ups + 4);
            u0.x += a.x; u0.y += a.y; u0.z += a.z; u0.w += a.w;
            u1.x += c.x; u1.y += c.y; u1.z += c.z; u1.w += c.w;
        }
    }

    float m_run = -1e30f, s_run = 0.f;
    float acc[8] = {0,0,0,0,0,0,0,0};
    #pragma unroll
    for (int i = 0; i < 8; i++) {
        const int n = r0 + i;
        float d = x[i][0].x*u0.x + x[i][0].y*u0.y + x[i][0].z*u0.z + x[i][0].w*u0.w
                + x[i][1].x*u1.x + x[i][1].y*u1.y + x[i][1].z*u1.z + x[i][1].w*u1.w;
        #pragma unroll
        for (int off = 32; off; off >>= 1) d += __shfl_xor(d, off);
        const float s = d * mk[i] * mk[i];      // ref masks e then en
        if (lane == 0) en[(size_t)b * NSRC + n] = s;
        const float mnew = fmaxf(m_run, s);
        const float sc = __expf(m_run - mnew);
        const float w  = __expf(s - mnew) * mk[i];
        s_run = s_run * sc + w;
        acc[0] = acc[0]*sc + w*x[i][0].x; acc[1] = acc[1]*sc + w*x[i][0].y;
        acc[2] = acc[2]*sc + w*x[i][0].z; acc[3] = acc[3]*sc + w*x[i][0].w;
        acc[4] = acc[4]*sc + w*x[i][1].x; acc[5] = acc[5]*sc + w*x[i][1].y;
        acc[6] = acc[6]*sc + w*x[i][1].z; acc[7] = acc[7]*sc + w*x[i][1].w;
        m_run = mnew;
    }
    __shared__ float sm[4], ss[4];
    __shared__ float sacc[4][512];
    *(float4*)&sacc[wv][lane*8]     = make_float4(acc[0], acc[1], acc[2], acc[3]);
    *(float4*)&sacc[wv][lane*8 + 4] = make_float4(acc[4], acc[5], acc[6], acc[7]);
    if (lane == 0) { sm[wv] = m_run; ss[wv] = s_run; }
    __syncthreads();
    const float M = fmaxf(fmaxf(sm[0], sm[1]), fmaxf(sm[2], sm[3]));
    const float e0 = __expf(sm[0]-M), e1 = __expf(sm[1]-M), e2 = __expf(sm[2]-M), e3 = __expf(sm[3]-M);
    const float S = ss[0]*e0 + ss[1]*e1 + ss[2]*e2 + ss[3]*e3;
    float* pp = part + (size_t)(b * 16 + chunk) * 514;
    const int c = t;
    pp[2 + c]       = sacc[0][c]*e0 + sacc[1][c]*e1 + sacc[2][c]*e2 + sacc[3][c]*e3;
    pp[2 + c + 256] = sacc[0][c+256]*e0 + sacc[1][c+256]*e1 + sacc[2][c+256]*e2 + sacc[3][c+256]*e3;
    if (t == 0) { pp[0] = M; pp[1] = S; }
}

// ---------------- combine chunk partials -> ctx (+ optional cat-half + attn weights) ----------------
// grid (64 batches, 4 d-chunks), 128 threads.
__global__ __launch_bounds__(128) void k_attn_combine(
    const float* __restrict__ part, const float* __restrict__ en,
    const float* __restrict__ mask, float* __restrict__ ctx,
    float* __restrict__ ctx2, float* __restrict__ attn_out)
{
    const int b = blockIdx.x, z = blockIdx.y, t = threadIdx.x;
    const float* pb = part + (size_t)b * 16 * 514;
    float M = -1e30f;
    #pragma unroll
    for (int c = 0; c < 16; c++) M = fmaxf(M, pb[c * 514]);
    float e[16]; float S = 0.f;
    #pragma unroll
    for (int c = 0; c < 16; c++) { e[c] = __expf(pb[c * 514] - M); S += pb[c * 514 + 1] * e[c]; }
    const float inv = 1.f / (S + 1e-10f);
    const int d = z * 128 + t;
    float a = 0.f;
    #pragma unroll
    for (int c = 0; c < 16; c++) a += pb[c * 514 + 2 + d] * e[c];
    const float val = a * inv;
    ctx[(size_t)b * 512 + d] = val;
    if (ctx2) ctx2[(size_t)b * 1024 + d] = val;
    if (attn_out)
        attn_out[(size_t)b * NSRC + d] = __expf(en[(size_t)b * NSRC + d] - M) * mask[(size_t)b * NSRC + d] * inv;
}

// ---------------- o1 partial-sum + f32->bf16 ----------------
__global__ void k_tobf16(const float* __restrict__ in, short* __restrict__ outp)
{
    const int i = blockIdx.x * 256 + threadIdx.x;  // 32768 total
    const float v = in[i] + in[32768 + i] + in[65536 + i] + in[98304 + i];
    outp[i] = f2bf(v);
}

// ---------------- out2: logits = A(64x512,bf16) @ W2(50000x512)^T + b2, bf16 MFMA ----------------
// Batch-split: grid (2 batch-halves, 391 ocol-parts), 512 thr. A-tile 32x512 bf16 = 32 KB
// -> 4 blocks/CU -> all 782 blocks resident (vs 391 blocks at 2/CU = 76% util before).
// Paired blocks (x=0/1, same y) read the same W2 rows, adjacent in dispatch order -> L2-hit.
// bf16 logits; per-block softmax stats -> bstat (same layout as before).
__global__ __launch_bounds__(512, 4) void k_out2_mfma(
    const short* __restrict__ Abf, const float* __restrict__ W2,
    const float* __restrict__ bias, short* __restrict__ Cb, float* __restrict__ bstat)
{
    __shared__ alignas(16) short As[32 * 512];    // 32 KB
    __shared__ float smax[8][32];
    __shared__ float ssum[8][32];
    const int t = threadIdx.x;
    const int lane = t & 63, wv = t >> 6;
    const int bh = blockIdx.x;            // batch half: rows [bh*32, bh*32+32)
    const int part = blockIdx.y;          // ocol part

    // Stage 32 rows x 512 cols bf16, swizzled LDS write.
    {
        char* Asb = (char*)As;
        const char* Ab = (const char*)Abf + (size_t)bh * 32 * 1024;
        #pragma unroll
        for (int it = 0; it < 4; ++it) {
            const int off = (it * 512 + t) * 16;
            const int row = off >> 10;
            const int kb  = off & 1023;
            bf16x8 v = *(const bf16x8*)(Ab + off);
            *(bf16x8*)(Asb + row * 1024 + (kb ^ ((row & 7) << 4))) = v;
        }
    }
    __syncthreads();

    const int l15 = lane & 15, g = lane >> 4;
    const int goff = g * 8;
    const int obase = part * 128 + wv * 16;
    const int ocol = obase + l15;
    const bool valid = (ocol < VOCAB);
    const int orow = valid ? ocol : (VOCAB - 1);
    const float* wr = &W2[(size_t)orow * RNN + goff];

    const int sw = (l15 & 7) << 4;
    const char* a0b = (const char*)As + (l15     ) * 1024;
    const char* a1b = (const char*)As + (l15 + 16) * 1024;

    f32x4 acc0 = {0,0,0,0}, acc1 = {0,0,0,0};

    float4 p0a = *(const float4*)(wr);
    float4 p0b = *(const float4*)(wr + 4);
    float4 p1a = *(const float4*)(wr + 32);
    float4 p1b = *(const float4*)(wr + 36);
    #pragma unroll 4
    for (int k0 = 0; k0 < RNN; k0 += 32) {
        const int kn = (k0 + 64) & 511;
        float4 n0 = *(const float4*)(wr + kn);
        float4 n1 = *(const float4*)(wr + kn + 4);
        const int kb = ((k0 + goff) * 2) ^ sw;
        bf16x8 a0 = *(const bf16x8*)(a0b + kb);
        bf16x8 a1 = *(const bf16x8*)(a1b + kb);
        bf16x8 bf;
        bf[0]=f2bf(p0a.x); bf[1]=f2bf(p0a.y); bf[2]=f2bf(p0a.z); bf[3]=f2bf(p0a.w);
        bf[4]=f2bf(p0b.x); bf[5]=f2bf(p0b.y); bf[6]=f2bf(p0b.z); bf[7]=f2bf(p0b.w);
        acc0 = __builtin_amdgcn_mfma_f32_16x16x32_bf16(a0, bf, acc0, 0, 0, 0);
        acc1 = __builtin_amdgcn_mfma_f32_16x16x32_bf16(a1, bf, acc1, 0, 0, 0);
        p0a = p1a; p0b = p1b; p1a = n0; p1b = n1;
    }

    // bf16-rounded logits; invalid lanes -> -1e30 sentinel (exp -> 0)
    const float bv = valid ? bias[ocol] : 0.f;
    short sb[2][4];
    float lv[2][4];
    #pragma unroll
    for (int r = 0; r < 4; r++) {
        sb[0][r] = f2bf(valid ? acc0[r] + bv : -1e30f);
        sb[1][r] = f2bf(valid ? acc1[r] + bv : -1e30f);
        lv[0][r] = bf2f(sb[0][r]);
        lv[1][r] = bf2f(sb[1][r]);
    }
    if (valid) {
        #pragma unroll
        for (int q = 0; q < 2; q++)
            #pragma unroll
            for (int r = 0; r < 4; r++)
                Cb[(size_t)(bh*32 + q*16 + g*4 + r) * VOCAB + ocol] = sb[q][r];
    }

    #pragma unroll
    for (int q = 0; q < 2; q++) {
        #pragma unroll
        for (int r = 0; r < 4; r++) {
            float m = lv[q][r];
            m = fmaxf(m, __shfl_xor(m, 1));
            m = fmaxf(m, __shfl_xor(m, 2));
            m = fmaxf(m, __shfl_xor(m, 4));
            m = fmaxf(m, __shfl_xor(m, 8));
            if (l15 == 0) smax[wv][q*16 + g*4 + r] = m;
        }
    }
    __syncthreads();
    if (t < 32) {
        float m = smax[0][t];
        #pragma unroll
        for (int w = 1; w < 8; w++) m = fmaxf(m, smax[w][t]);
        smax[0][t] = m;
    }
    __syncthreads();
    #pragma unroll
    for (int q = 0; q < 2; q++) {
        #pragma unroll
        for (int r = 0; r < 4; r++) {
            const int row = q*16 + g*4 + r;
            float e = __expf(lv[q][r] - smax[0][row]);
            e += __shfl_xor(e, 1);
            e += __shfl_xor(e, 2);
            e += __shfl_xor(e, 4);
            e += __shfl_xor(e, 8);
            if (l15 == 0) ssum[wv][row] = e;
        }
    }
    __syncthreads();
    if (t < 32) {
        float s = 0.f;
        #pragma unroll
        for (int w = 0; w < 8; w++) s += ssum[w][t];
        const int grow = bh * 32 + t;
        bstat[((size_t)grow * NOB2 + part) * 2 + 0] = smax[0][t];
        bstat[((size_t)grow * NOB2 + part) * 2 + 1] = s;
    }
}

// ---------------- reduce per-block stats -> per-row (max, sum) ----------------
__global__ __launch_bounds__(256) void k_statred(const float* __restrict__ bstat, float* __restrict__ stat)
{
    const int b = blockIdx.x, t = threadIdx.x;
    const float* pr = bstat + (size_t)b * NOB2 * 2;
    __shared__ float red[8];
    float m = -1e30f;
    for (int i = t; i < NOB2; i += 256) m = fmaxf(m, pr[i*2]);
    #pragma unroll
    for (int off = 32; off; off >>= 1) m = fmaxf(m, __shfl_xor(m, off));
    if ((t & 63) == 0) red[t >> 6] = m;
    __syncthreads();
    m = fmaxf(fmaxf(red[0], red[1]), fmaxf(red[2], red[3]));
    __syncthreads();
    float s = 0.f;
    for (int i = t; i < NOB2; i += 256) s += pr[i*2+1] * __expf(pr[i*2] - m);
    #pragma unroll
    for (int off = 32; off; off >>= 1) s += __shfl_xor(s, off);
    if ((t & 63) == 0) red[(t >> 6) + 4] = s;
    __syncthreads();
    if (t == 0) { stat[b*2] = m; stat[b*2+1] = red[4]+red[5]+red[6]+red[7]; }
}

// ---------------- final_dist = 0.5*softmax(bf16 logits) ++ extra_zeros, + fused scatter ----------------
// Fully OVERWRITES out (replay-safe). Scatter contributions accumulated per-block in LDS.
// grid (25, 64), 256 thr, 8 elems/thread.
__global__ __launch_bounds__(256) void k_final(
    const short* __restrict__ Lb, const float* __restrict__ stat,
    const float* __restrict__ ez, const int* __restrict__ idx,
    const float* __restrict__ attn, float* __restrict__ out)
{
    __shared__ float sadd[2048];
    const int b = blockIdx.y, t = threadIdx.x;
    const int base = blockIdx.x * 2048;
    #pragma unroll
    for (int i = 0; i < 8; i++) sadd[t + i * 256] = 0.f;
    __syncthreads();
    for (int j = t; j < NSRC; j += 256) {
        const int v = idx[(size_t)b * NSRC + j];
        const int loc = v - base;
        if ((unsigned)loc < 2048u)
            atomicAdd(&sadd[loc], 0.5f * attn[(size_t)b * NSRC + j]);
    }
    __syncthreads();

    const float m = stat[b * 2];
    const float inv = 0.5f / stat[b * 2 + 1];
    const int v0 = base + t * 8;
    if (v0 >= VEXT) return;
    float* op = out + (size_t)b * VEXT + v0;
    const float* sp = &sadd[t * 8];
    if (v0 + 8 <= VOCAB) {
        bf16x8 x = *(const bf16x8*)&Lb[(size_t)b * VOCAB + v0];
        float2 r0 = make_float2(__expf(bf2f(x[0]) - m) * inv + sp[0], __expf(bf2f(x[1]) - m) * inv + sp[1]);
        float2 r1 = make_float2(__expf(bf2f(x[2]) - m) * inv + sp[2], __expf(bf2f(x[3]) - m) * inv + sp[3]);
        float2 r2 = make_float2(__expf(bf2f(x[4]) - m) * inv + sp[4], __expf(bf2f(x[5]) - m) * inv + sp[5]);
        float2 r3 = make_float2(__expf(bf2f(x[6]) - m) * inv + sp[6], __expf(bf2f(x[7]) - m) * inv + sp[7]);
        *(float2*)(op)     = r0;
        *(float2*)(op + 2) = r1;
        *(float2*)(op + 4) = r2;
        *(float2*)(op + 6) = r3;
    } else {
        #pragma unroll
        for (int e = 0; e < 8; e++) {
            const int v = v0 + e;
            if (v >= VEXT) break;
            float r;
            if (v < VOCAB) r = __expf(bf2f(Lb[(size_t)b * VOCAB + v]) - m) * inv;
            else           r = ez[(size_t)b * OOV + (v - VOCAB)];
            op[e] = r + sp[e];
        }
    }
}

extern "C" void kernel_launch(void* const* d_in, const int* in_sizes, int n_in,
                              void* d_out, int out_size, void* d_ws, size_t ws_size,
                              hipStream_t stream)
{
    (void)in_sizes; (void)n_in; (void)out_size; (void)ws_size;
    const int*   y     = (const int*)  d_in[0];
    const float* st1   = (const float*)d_in[1];
    const float* enc   = (const float*)d_in[2];
    const float* encM  = (const float*)d_in[3];
    const float* ct1   = (const float*)d_in[4];
    const float* ez    = (const float*)d_in[5];
    const int*   ebev  = (const int*)  d_in[6];
    const float* qmem  = (const float*)d_in[7];
    const float* qmask = (const float*)d_in[8];
    const float* emb   = (const float*)d_in[9];
    const float* xw    = (const float*)d_in[10];
    const float* xb    = (const float*)d_in[11];
    const float* wih   = (const float*)d_in[12];
    const float* whh   = (const float*)d_in[13];
    const float* bih   = (const float*)d_in[14];
    const float* bhh   = (const float*)d_in[15];
    const float* rqw   = (const float*)d_in[16];
    const float* rsw   = (const float*)d_in[17];
    const float* o1w   = (const float*)d_in[18];
    const float* o1b   = (const float*)d_in[19];
    const float* o2w   = (const float*)d_in[20];
    const float* o2b   = (const float*)d_in[21];

    float* ws  = (float*)d_ws;
    float* out = (float*)d_out;

    // region A (transient, dead before out2; overlapped by bf16 logits)
    constexpr size_t WS_PART = 0;         // 64*16*514 = 526336
    constexpr size_t WS_EN   = 526336;    // 32768
    constexpr size_t WS_H1   = 559104;    // 32768
    constexpr size_t WS_CTX1 = 591872;    // 32768 (ends 624640)
    constexpr size_t WS_LOG  = 0;         // bf16: 64*50000*2B = 1.6M float slots (overlaps region A)
    // region P (persistent, packed with liveness overlays)
    constexpr size_t WS_GIP  = 3200000;   // 4*64*1536 (both GRU steps)
    constexpr size_t WS_GHP  = 3593216;   // 4*64*1536
    constexpr size_t WS_UP   = 3986432;   // 8*64*512 = 262144 (live u-gemm..attn)
    constexpr size_t WS_XP   = 3986432;   // overlay: 4*64*512, live x0gemm..gi-gemm (before UP)
    constexpr size_t WS_O1P  = 3986432;   // overlay: 4*64*512, live o1gemm..tobf16 (after UP)
    constexpr size_t WS_ABF  = 4117504;   // overlay: 16384 float slots, live tobf16..out2
    constexpr size_t WS_CAT2 = 4248576;   // 64*1024
    constexpr size_t WS_BSTAT= 4314112;   // 64*391*2 = 50048
    constexpr size_t WS_STAT = 4364160;   // 128 (ends 4364288)

    constexpr size_t OUT_ST = 3203200, OUT_CT = 3235968, OUT_ATTN = 3268736;

    float* part = ws + WS_PART;
    float* en   = ws + WS_EN;
    float* h1   = ws + WS_H1;
    float* ctx1 = ws + WS_CTX1;
    short* logi = (short*)(ws + WS_LOG);
    float* gip  = ws + WS_GIP;
    float* ghp  = ws + WS_GHP;
    float* up   = ws + WS_UP;
    float* xp   = ws + WS_XP;
    float* o1p  = ws + WS_O1P;
    float* cat2 = ws + WS_CAT2;
    float* bstat= ws + WS_BSTAT;
    float* stat = ws + WS_STAT;
    short* abf  = (short*)(ws + WS_ABF);

    // 1. x = [c_t_1, emb[y]] @ x_ctx_w.T + b   (fused gather, K=1024, O=512)
    k_gemm_x0<<<dim3(16,4), 256, 0, stream>>>(y, ct1, emb, xw, xb, xp);
    // 2. gi = x@wih.T+bih ; gh = h0@whh.T+bhh   (z=2)
    k_gemm_small<true><<<dim3(48,4,2), 256, 0, stream>>>(xp, wih, bih, gip, 1,
                                                         st1, whh, bhh, ghp, 0, 512, 1536);
    // 3. h1 = GRU1 (fused); u1 = h1 @ readq_w   (k-split 8)
    k_gemm_gru<8><<<dim3(16,8), 256, 0, stream>>>(gip, ghp, st1, rqw, up, h1, nullptr);
    // 4/5. attention over query_memory -> ctx1
    k_attn_pass<<<dim3(16,64), 256, 0, stream>>>(qmem, up, qmask, en, part);
    k_attn_combine<<<dim3(64,4), 128, 0, stream>>>(part, en, qmask, ctx1, nullptr, nullptr);
    // 6. gi2 = ctx1@wih.T+bih ; gh2 = h1@whh.T+bhh
    k_gemm_small<true><<<dim3(48,4,2), 256, 0, stream>>>(ctx1, wih, bih, gip, 0,
                                                         h1, whh, bhh, ghp, 0, 512, 1536);
    // 7. h2 = GRU2 (fused, writes s_t + cat2 left); u2 = h2 @ readsrc_w
    k_gemm_gru<8><<<dim3(16,8), 256, 0, stream>>>(gip, ghp, h1, rsw, up, out + OUT_ST, cat2);
    // 8/9. attention over encoder_outputs -> c_t, attn_dist, cat2 right half
    k_attn_pass<<<dim3(16,64), 256, 0, stream>>>(enc, up, encM, en, part);
    k_attn_combine<<<dim3(64,4), 128, 0, stream>>>(part, en, encM, out + OUT_CT, cat2 + 512, out + OUT_ATTN);
    // 10. o1 = cat2 @ out1_w.T + b  (K=1024, O=512) -> 4 partial slices
    k_gemm_small<true><<<dim3(16,4,1), 256, 0, stream>>>(cat2, o1w, o1b, o1p, 0,
                                                         nullptr, nullptr, nullptr, nullptr, 0, 1024, 512);
    // 11. sum o1 partials -> bf16 (64 KB broadcast source for out2 — R9 lesson)
    k_tobf16<<<128, 256, 0, stream>>>(o1p, abf);
    // 12. logits (bf16) + per-block softmax stats (batch-split: 782 blocks all resident)
    k_out2_mfma<<<dim3(2, NOB2), 512, 0, stream>>>(abf, o2w, o2b, logi, bstat);
    // 13. fold block stats -> per-row (M, S)
    k_statred<<<64, 256, 0, stream>>>(bstat, stat);
    // 14. final_dist = 0.5*softmax ++ extra_zeros, + LDS-fused scatter (overwrite; replay-safe)
    k_final<<<dim3(25,64), 256, 0, stream>>>(logi, stat, ez, ebev, out + OUT_ATTN, out);
}

// Round 12
// 149.313 us; speedup vs baseline: 1.1277x; 1.1277x over previous
//
#include <hip/hip_runtime.h>

#define BATCH 64
#define RNN   512
#define VOCAB 50000
#define OOV   50
#define VEXT  50050
#define NSRC  512
#define NOB2  391   // out2 blocks

typedef short bf16x8 __attribute__((ext_vector_type(8)));
typedef float f32x4  __attribute__((ext_vector_type(4)));

__device__ __forceinline__ float sigmoidf_(float x) { return 1.f / (1.f + __expf(-x)); }

__device__ __forceinline__ float gru_one(float ir, float iz, float inn,
                                         float hr, float hz, float hn, float h)
{
    const float r = sigmoidf_(ir + hr);
    const float z = sigmoidf_(iz + hz);
    const float n = tanhf(inn + r * hn);
    return (1.f - z) * n + z * h;
}

__device__ __forceinline__ short f2bf(float x) {
    unsigned u = __builtin_bit_cast(unsigned, x);
    unsigned r = (u + 0x7FFFu + ((u >> 16) & 1u)) >> 16;
    return (short)r;
}
__device__ __forceinline__ float bf2f(short s) {
    unsigned u = ((unsigned)(unsigned short)s) << 16;
    return __builtin_bit_cast(float, u);
}

// ---------------- small GEMM: C[b,o] = sum_k A[b,k] * W(o,k) (+bias) ----------------
// WT=true : W is (O,K) row-major (PyTorch Linear layout, x@W.T)
// grid = (O/32, KSPLIT, nz), kchunk = K/gridDim.y. Writes PARTIALS: C + blockIdx.y*64*O.
// asum = slice COUNT: A is asum partial slices [asum][64][K] summed while staging (0/1 = plain).
// FAILED-EXPERIMENT LOG (do not retry): register-prefetch (R4: s_t absmax 1.9e-2);
// per-block __threadfence completion fusion (R7: 3.8x, L2-writeback serialization);
// scatter-into-output accumulate (R8: replay-idempotence); consumer-side o1p f32
// staging in out2 (R9: 391x512KB re-read, +35us); out2 batch-split (R11: +15.5us,
// XCD round-robin duplicates the W2 stream).
template<bool WT>
__global__ __launch_bounds__(256) void k_gemm_small(
    const float* __restrict__ A0, const float* __restrict__ W0,
    const float* __restrict__ bias0, float* __restrict__ C0, int asum0,
    const float* __restrict__ A1, const float* __restrict__ W1,
    const float* __restrict__ bias1, float* __restrict__ C1, int asum1,
    int K, int O)
{
    const float* A = A0; const float* W = W0; const float* bias = bias0;
    float* C = C0; int asum = asum0;
    if (blockIdx.z == 1) { A = A1; W = W1; bias = bias1; C = C1; asum = asum1; }

    __shared__ float As[32 * 64];   // [k][b]
    __shared__ float Ws[32 * 32];   // [k][o]
    const int t  = threadIdx.x;
    const int tx = t & 15, ty = t >> 4;
    const int o0 = blockIdx.x * 32;
    const int kchunk = K / gridDim.y;
    const int kbeg = blockIdx.y * kchunk;
    const int kend = kbeg + kchunk;
    float acc[4][2] = {};
    const int ab  = t >> 2;         // 0..63
    const int akq = (t & 3) * 4;    // 0,4,8,12

    for (int k0 = kbeg; k0 < kend; k0 += 32) {
        {
            const float* Ap = &A[(size_t)ab * K + k0 + akq];
            float4 v0 = *(const float4*)Ap;
            float4 v1 = *(const float4*)(Ap + 16);
            for (int s = 1; s < asum; s++) {
                const float* Aps = Ap + (size_t)s * 64 * K;
                float4 w0 = *(const float4*)Aps;
                float4 w1 = *(const float4*)(Aps + 16);
                v0.x += w0.x; v0.y += w0.y; v0.z += w0.z; v0.w += w0.w;
                v1.x += w1.x; v1.y += w1.y; v1.z += w1.z; v1.w += w1.w;
            }
            As[(akq+0)*64+ab]=v0.x; As[(akq+1)*64+ab]=v0.y; As[(akq+2)*64+ab]=v0.z; As[(akq+3)*64+ab]=v0.w;
            As[(akq+16)*64+ab]=v1.x; As[(akq+17)*64+ab]=v1.y; As[(akq+18)*64+ab]=v1.z; As[(akq+19)*64+ab]=v1.w;
        }
        if (WT) {
            const int o  = t >> 3;          // 0..31
            const int kq = (t & 7) * 4;     // 0..28
            float4 v = *(const float4*)&W[(size_t)(o0 + o) * K + k0 + kq];
            Ws[(kq+0)*32+o]=v.x; Ws[(kq+1)*32+o]=v.y; Ws[(kq+2)*32+o]=v.z; Ws[(kq+3)*32+o]=v.w;
        } else {
            const int kk = t >> 3;          // 0..31
            const int oq = (t & 7) * 4;
            *(float4*)&Ws[kk*32 + oq] = *(const float4*)&W[(size_t)(k0 + kk) * O + o0 + oq];
        }
        __syncthreads();
        #pragma unroll
        for (int kk = 0; kk < 32; kk++) {
            float4 a4 = *(const float4*)&As[kk*64 + ty*4];
            float2 w2 = *(const float2*)&Ws[kk*32 + tx*2];
            acc[0][0] = fmaf(a4.x, w2.x, acc[0][0]); acc[0][1] = fmaf(a4.x, w2.y, acc[0][1]);
            acc[1][0] = fmaf(a4.y, w2.x, acc[1][0]); acc[1][1] = fmaf(a4.y, w2.y, acc[1][1]);
            acc[2][0] = fmaf(a4.z, w2.x, acc[2][0]); acc[2][1] = fmaf(a4.z, w2.y, acc[2][1]);
            acc[3][0] = fmaf(a4.w, w2.x, acc[3][0]); acc[3][1] = fmaf(a4.w, w2.y, acc[3][1]);
        }
        __syncthreads();
    }
    const int o = o0 + tx*2;
    float b0v = 0.f, b1v = 0.f;
    if (bias && blockIdx.y == 0) { b0v = bias[o]; b1v = bias[o+1]; }
    float* Cp = C + (size_t)blockIdx.y * 64 * O;
    #pragma unroll
    for (int j = 0; j < 4; j++) {
        const int bb = ty*4 + j;
        Cp[(size_t)bb*O + o]     = acc[j][0] + b0v;
        Cp[(size_t)bb*O + o + 1] = acc[j][1] + b1v;
    }
}

// ---------------- GEMM with fused x0 gather: x = [c_t_1, emb[y]] @ W.T + b ----------------
// K=1024, O=512, W (O,K) row-major, grid (16, KSPLIT), partials to C + y*64*512.
__global__ __launch_bounds__(256) void k_gemm_x0(
    const int* __restrict__ yidx, const float* __restrict__ ct1, const float* __restrict__ emb,
    const float* __restrict__ W, const float* __restrict__ bias, float* __restrict__ C)
{
    __shared__ float As[32 * 64];
    __shared__ float Ws[32 * 32];
    const int t  = threadIdx.x;
    const int tx = t & 15, ty = t >> 4;
    const int o0 = blockIdx.x * 32;
    const int kchunk = 1024 / gridDim.y;
    const int kbeg = blockIdx.y * kchunk;
    const int kend = kbeg + kchunk;
    float acc[4][2] = {};
    const int ab  = t >> 2;
    const int akq = (t & 3) * 4;
    const int erow = yidx[ab];

    for (int k0 = kbeg; k0 < kend; k0 += 32) {
        {
            // tile [k0,k0+32) lies entirely in one half (512 % 32 == 0)
            const float* src = (k0 < 512) ? (ct1 + (size_t)ab * 512 + k0)
                                          : (emb + (size_t)erow * 512 + (k0 - 512));
            float4 v0 = *(const float4*)(src + akq);
            float4 v1 = *(const float4*)(src + akq + 16);
            As[(akq+0)*64+ab]=v0.x; As[(akq+1)*64+ab]=v0.y; As[(akq+2)*64+ab]=v0.z; As[(akq+3)*64+ab]=v0.w;
            As[(akq+16)*64+ab]=v1.x; As[(akq+17)*64+ab]=v1.y; As[(akq+18)*64+ab]=v1.z; As[(akq+19)*64+ab]=v1.w;
        }
        {
            const int o  = t >> 3;
            const int kq = (t & 7) * 4;
            float4 v = *(const float4*)&W[(size_t)(o0 + o) * 1024 + k0 + kq];
            Ws[(kq+0)*32+o]=v.x; Ws[(kq+1)*32+o]=v.y; Ws[(kq+2)*32+o]=v.z; Ws[(kq+3)*32+o]=v.w;
        }
        __syncthreads();
        #pragma unroll
        for (int kk = 0; kk < 32; kk++) {
            float4 a4 = *(const float4*)&As[kk*64 + ty*4];
            float2 w2 = *(const float2*)&Ws[kk*32 + tx*2];
            acc[0][0] = fmaf(a4.x, w2.x, acc[0][0]); acc[0][1] = fmaf(a4.x, w2.y, acc[0][1]);
            acc[1][0] = fmaf(a4.y, w2.x, acc[1][0]); acc[1][1] = fmaf(a4.y, w2.y, acc[1][1]);
            acc[2][0] = fmaf(a4.z, w2.x, acc[2][0]); acc[2][1] = fmaf(a4.z, w2.y, acc[2][1]);
            acc[3][0] = fmaf(a4.w, w2.x, acc[3][0]); acc[3][1] = fmaf(a4.w, w2.y, acc[3][1]);
        }
        __syncthreads();
    }
    const int o = o0 + tx*2;
    float b0v = 0.f, b1v = 0.f;
    if (blockIdx.y == 0) { b0v = bias[o]; b1v = bias[o+1]; }
    float* Cp = C + (size_t)blockIdx.y * 64 * 512;
    #pragma unroll
    for (int j = 0; j < 4; j++) {
        const int bb = ty*4 + j;
        Cp[(size_t)bb*512 + o]     = acc[j][0] + b0v;
        Cp[(size_t)bb*512 + o + 1] = acc[j][1] + b1v;
    }
}

// ---------------- GEMM with fused GRU: u = GRU(gi,gh,hprev) @ W ----------------
// gi/gh are 4 k-split partial slices [4][64][1536]. W (K,O)=(512,512) row-major (x@W).
// grid (16, KS), 256 thr. Partials to C + y*64*512. Block x==0 also writes h (+cat).
template<int KS>
__global__ __launch_bounds__(256) void k_gemm_gru(
    const float* __restrict__ gi, const float* __restrict__ gh,
    const float* __restrict__ hprev, const float* __restrict__ W,
    float* __restrict__ C, float* __restrict__ hout, float* __restrict__ cat_out)
{
    __shared__ float As[32 * 64];
    __shared__ float Ws[32 * 32];
    const int t  = threadIdx.x;
    const int tx = t & 15, ty = t >> 4;
    const int o0 = blockIdx.x * 32;
    const int kchunk = 512 / KS;
    const int kbeg = blockIdx.y * kchunk;
    const int kend = kbeg + kchunk;
    float acc[4][2] = {};
    const int ab  = t >> 2;
    const int akq = (t & 3) * 4;

    for (int k0 = kbeg; k0 < kend; k0 += 32) {
        #pragma unroll
        for (int half = 0; half < 2; half++) {
            const int d = k0 + akq + half * 16;
            float irv[4] = {0,0,0,0}, izv[4] = {0,0,0,0}, inv_[4] = {0,0,0,0};
            float hrv[4] = {0,0,0,0}, hzv[4] = {0,0,0,0}, hnv[4] = {0,0,0,0};
            #pragma unroll
            for (int s = 0; s < 4; s++) {
                const float* gp = gi + (size_t)s * BATCH * 1536 + (size_t)ab * 1536 + d;
                const float* hp = gh + (size_t)s * BATCH * 1536 + (size_t)ab * 1536 + d;
                float4 a0 = *(const float4*)(gp);
                float4 a1 = *(const float4*)(gp + 512);
                float4 a2 = *(const float4*)(gp + 1024);
                float4 b0 = *(const float4*)(hp);
                float4 b1 = *(const float4*)(hp + 512);
                float4 b2 = *(const float4*)(hp + 1024);
                irv[0]+=a0.x; irv[1]+=a0.y; irv[2]+=a0.z; irv[3]+=a0.w;
                izv[0]+=a1.x; izv[1]+=a1.y; izv[2]+=a1.z; izv[3]+=a1.w;
                inv_[0]+=a2.x; inv_[1]+=a2.y; inv_[2]+=a2.z; inv_[3]+=a2.w;
                hrv[0]+=b0.x; hrv[1]+=b0.y; hrv[2]+=b0.z; hrv[3]+=b0.w;
                hzv[0]+=b1.x; hzv[1]+=b1.y; hzv[2]+=b1.z; hzv[3]+=b1.w;
                hnv[0]+=b2.x; hnv[1]+=b2.y; hnv[2]+=b2.z; hnv[3]+=b2.w;
            }
            const float4 hq = *(const float4*)(hprev + (size_t)ab * 512 + d);
            float o0v = gru_one(irv[0], izv[0], inv_[0], hrv[0], hzv[0], hnv[0], hq.x);
            float o1v = gru_one(irv[1], izv[1], inv_[1], hrv[1], hzv[1], hnv[1], hq.y);
            float o2v = gru_one(irv[2], izv[2], inv_[2], hrv[2], hzv[2], hnv[2], hq.z);
            float o3v = gru_one(irv[3], izv[3], inv_[3], hrv[3], hzv[3], hnv[3], hq.w);
            const int kk = akq + half * 16;
            As[(kk+0)*64+ab] = o0v; As[(kk+1)*64+ab] = o1v;
            As[(kk+2)*64+ab] = o2v; As[(kk+3)*64+ab] = o3v;
            if (blockIdx.x == 0) {
                float4 ov = make_float4(o0v, o1v, o2v, o3v);
                *(float4*)&hout[(size_t)ab * 512 + d] = ov;
                if (cat_out) *(float4*)&cat_out[(size_t)ab * 1024 + d] = ov;
            }
        }
        {
            const int kk = t >> 3;
            const int oq = (t & 7) * 4;
            *(float4*)&Ws[kk*32 + oq] = *(const float4*)&W[(size_t)(k0 + kk) * 512 + o0 + oq];
        }
        __syncthreads();
        #pragma unroll
        for (int kk = 0; kk < 32; kk++) {
            float4 a4 = *(const float4*)&As[kk*64 + ty*4];
            float2 w2 = *(const float2*)&Ws[kk*32 + tx*2];
            acc[0][0] = fmaf(a4.x, w2.x, acc[0][0]); acc[0][1] = fmaf(a4.x, w2.y, acc[0][1]);
            acc[1][0] = fmaf(a4.y, w2.x, acc[1][0]); acc[1][1] = fmaf(a4.y, w2.y, acc[1][1]);
            acc[2][0] = fmaf(a4.z, w2.x, acc[2][0]); acc[2][1] = fmaf(a4.z, w2.y, acc[2][1]);
            acc[3][0] = fmaf(a4.w, w2.x, acc[3][0]); acc[3][1] = fmaf(a4.w, w2.y, acc[3][1]);
        }
        __syncthreads();
    }
    const int o = o0 + tx*2;
    float* Cp = C + (size_t)blockIdx.y * 64 * 512;
    #pragma unroll
    for (int j = 0; j < 4; j++) {
        const int bb = ty*4 + j;
        Cp[(size_t)bb*512 + o]     = acc[j][0];
        Cp[(size_t)bb*512 + o + 1] = acc[j][1];
    }
}

// ---------------- fused attention pass ----------------
__global__ __launch_bounds__(256) void k_attn_pass(
    const float* __restrict__ KV, const float* __restrict__ Upart,
    const float* __restrict__ mask, float* __restrict__ en, float* __restrict__ part)
{
    const int b = blockIdx.y;
    const int chunk = blockIdx.x;
    const int t = threadIdx.x;
    const int lane = t & 63;
    const int wv = t >> 6;
    const float* KVb = KV + (size_t)b * NSRC * RNN;

    const int r0 = chunk * 32 + wv * 8;

    float4 x[8][2];
    float mk[8];
    #pragma unroll
    for (int i = 0; i < 8; i++) {
        const float* rp = KVb + (size_t)(r0 + i) * RNN + lane * 8;
        x[i][0] = *(const float4*)rp;
        x[i][1] = *(const float4*)(rp + 4);
    }
    #pragma unroll
    for (int i = 0; i < 8; i++) mk[i] = mask[(size_t)b * NSRC + r0 + i];

    float4 u0, u1;
    {
        const float* up = Upart + (size_t)b * RNN + lane * 8;
        u0 = *(const float4*)up; u1 = *(const float4*)(up + 4);
        #pragma unroll
        for (int s = 1; s < 8; s++) {
            const float* ups = up + (size_t)s * BATCH * RNN;
            float4 a = *(const float4*)ups; float4 c = *(const float4*)(ups + 4);
            u0.x += a.x; u0.y += a.y; u0.z += a.z; u0.w += a.w;
            u1.x += c.x; u1.y += c.y; u1.z += c.z; u1.w += c.w;
        }
    }

    float m_run = -1e30f, s_run = 0.f;
    float acc[8] = {0,0,0,0,0,0,0,0};
    #pragma unroll
    for (int i = 0; i < 8; i++) {
        const int n = r0 + i;
        float d = x[i][0].x*u0.x + x[i][0].y*u0.y + x[i][0].z*u0.z + x[i][0].w*u0.w
                + x[i][1].x*u1.x + x[i][1].y*u1.y + x[i][1].z*u1.z + x[i][1].w*u1.w;
        #pragma unroll
        for (int off = 32; off; off >>= 1) d += __shfl_xor(d, off);
        const float s = d * mk[i] * mk[i];      // ref masks e then en
        if (lane == 0) en[(size_t)b * NSRC + n] = s;
        const float mnew = fmaxf(m_run, s);
        const float sc = __expf(m_run - mnew);
        const float w  = __expf(s - mnew) * mk[i];
        s_run = s_run * sc + w;
        acc[0] = acc[0]*sc + w*x[i][0].x; acc[1] = acc[1]*sc + w*x[i][0].y;
        acc[2] = acc[2]*sc + w*x[i][0].z; acc[3] = acc[3]*sc + w*x[i][0].w;
        acc[4] = acc[4]*sc + w*x[i][1].x; acc[5] = acc[5]*sc + w*x[i][1].y;
        acc[6] = acc[6]*sc + w*x[i][1].z; acc[7] = acc[7]*sc + w*x[i][1].w;
        m_run = mnew;
    }
    __shared__ float sm[4], ss[4];
    __shared__ float sacc[4][512];
    *(float4*)&sacc[wv][lane*8]     = make_float4(acc[0], acc[1], acc[2], acc[3]);
    *(float4*)&sacc[wv][lane*8 + 4] = make_float4(acc[4], acc[5], acc[6], acc[7]);
    if (lane == 0) { sm[wv] = m_run; ss[wv] = s_run; }
    __syncthreads();
    const float M = fmaxf(fmaxf(sm[0], sm[1]), fmaxf(sm[2], sm[3]));
    const float e0 = __expf(sm[0]-M), e1 = __expf(sm[1]-M), e2 = __expf(sm[2]-M), e3 = __expf(sm[3]-M);
    const float S = ss[0]*e0 + ss[1]*e1 + ss[2]*e2 + ss[3]*e3;
    float* pp = part + (size_t)(b * 16 + chunk) * 514;
    const int c = t;
    pp[2 + c]       = sacc[0][c]*e0 + sacc[1][c]*e1 + sacc[2][c]*e2 + sacc[3][c]*e3;
    pp[2 + c + 256] = sacc[0][c+256]*e0 + sacc[1][c+256]*e1 + sacc[2][c+256]*e2 + sacc[3][c+256]*e3;
    if (t == 0) { pp[0] = M; pp[1] = S; }
}

// ---------------- combine chunk partials -> ctx (+ optional cat-half + attn weights) ----------------
// grid (64 batches, 4 d-chunks), 128 threads.
__global__ __launch_bounds__(128) void k_attn_combine(
    const float* __restrict__ part, const float* __restrict__ en,
    const float* __restrict__ mask, float* __restrict__ ctx,
    float* __restrict__ ctx2, float* __restrict__ attn_out)
{
    const int b = blockIdx.x, z = blockIdx.y, t = threadIdx.x;
    const float* pb = part + (size_t)b * 16 * 514;
    float M = -1e30f;
    #pragma unroll
    for (int c = 0; c < 16; c++) M = fmaxf(M, pb[c * 514]);
    float e[16]; float S = 0.f;
    #pragma unroll
    for (int c = 0; c < 16; c++) { e[c] = __expf(pb[c * 514] - M); S += pb[c * 514 + 1] * e[c]; }
    const float inv = 1.f / (S + 1e-10f);
    const int d = z * 128 + t;
    float a = 0.f;
    #pragma unroll
    for (int c = 0; c < 16; c++) a += pb[c * 514 + 2 + d] * e[c];
    const float val = a * inv;
    ctx[(size_t)b * 512 + d] = val;
    if (ctx2) ctx2[(size_t)b * 1024 + d] = val;
    if (attn_out)
        attn_out[(size_t)b * NSRC + d] = __expf(en[(size_t)b * NSRC + d] - M) * mask[(size_t)b * NSRC + d] * inv;
}

// ---------------- o1 partial-sum (8 slices) + f32->bf16 ----------------
__global__ void k_tobf16(const float* __restrict__ in, short* __restrict__ outp)
{
    const int i = blockIdx.x * 256 + threadIdx.x;  // 32768 total
    float v = 0.f;
    #pragma unroll
    for (int s = 0; s < 8; s++) v += in[s * 32768 + i];
    outp[i] = f2bf(v);
}

// ---------------- out2: logits = A(64x512,bf16) @ W2(50000x512)^T + b2, bf16 MFMA ----------------
// R10-proven form: 391 blocks x 512 thr, all resident (2/CU, 64 KB LDS); single pass
// over W2 (no batch split — R11 lesson). bf16 logits; per-block stats -> bstat.
__global__ __launch_bounds__(512, 4) void k_out2_mfma(
    const short* __restrict__ Abf, const float* __restrict__ W2,
    const float* __restrict__ bias, short* __restrict__ Cb, float* __restrict__ bstat)
{
    __shared__ alignas(16) short As[64 * 512];    // 64 KB
    __shared__ float smax[8][64];
    __shared__ float ssum[8][64];
    const int t = threadIdx.x;
    const int lane = t & 63, wv = t >> 6;

    {
        char* Asb = (char*)As;
        const char* Ab = (const char*)Abf;
        #pragma unroll
        for (int it = 0; it < 8; ++it) {
            const int off = (it * 512 + t) * 16;
            const int row = off >> 10;
            const int kb  = off & 1023;
            bf16x8 v = *(const bf16x8*)(Ab + off);
            *(bf16x8*)(Asb + row * 1024 + (kb ^ ((row & 7) << 4))) = v;
        }
    }
    __syncthreads();

    const int l15 = lane & 15, g = lane >> 4;
    const int goff = g * 8;
    const int obase = blockIdx.x * 128 + wv * 16;
    const int ocol = obase + l15;
    const bool valid = (ocol < VOCAB);
    const int orow = valid ? ocol : (VOCAB - 1);
    const float* wr = &W2[(size_t)orow * RNN + goff];

    const int sw = (l15 & 7) << 4;
    const char* a0b = (const char*)As + (l15     ) * 1024;
    const char* a1b = (const char*)As + (l15 + 16) * 1024;
    const char* a2b = (const char*)As + (l15 + 32) * 1024;
    const char* a3b = (const char*)As + (l15 + 48) * 1024;

    f32x4 acc0 = {0,0,0,0}, acc1 = {0,0,0,0}, acc2 = {0,0,0,0}, acc3 = {0,0,0,0};

    float4 p0a = *(const float4*)(wr);
    float4 p0b = *(const float4*)(wr + 4);
    float4 p1a = *(const float4*)(wr + 32);
    float4 p1b = *(const float4*)(wr + 36);
    #pragma unroll 4
    for (int k0 = 0; k0 < RNN; k0 += 32) {
        const int kn = (k0 + 64) & 511;
        float4 n0 = *(const float4*)(wr + kn);
        float4 n1 = *(const float4*)(wr + kn + 4);
        const int kb = ((k0 + goff) * 2) ^ sw;
        bf16x8 a0 = *(const bf16x8*)(a0b + kb);
        bf16x8 a1 = *(const bf16x8*)(a1b + kb);
        bf16x8 a2 = *(const bf16x8*)(a2b + kb);
        bf16x8 a3 = *(const bf16x8*)(a3b + kb);
        bf16x8 bf;
        bf[0]=f2bf(p0a.x); bf[1]=f2bf(p0a.y); bf[2]=f2bf(p0a.z); bf[3]=f2bf(p0a.w);
        bf[4]=f2bf(p0b.x); bf[5]=f2bf(p0b.y); bf[6]=f2bf(p0b.z); bf[7]=f2bf(p0b.w);
        acc0 = __builtin_amdgcn_mfma_f32_16x16x32_bf16(a0, bf, acc0, 0, 0, 0);
        acc1 = __builtin_amdgcn_mfma_f32_16x16x32_bf16(a1, bf, acc1, 0, 0, 0);
        acc2 = __builtin_amdgcn_mfma_f32_16x16x32_bf16(a2, bf, acc2, 0, 0, 0);
        acc3 = __builtin_amdgcn_mfma_f32_16x16x32_bf16(a3, bf, acc3, 0, 0, 0);
        p0a = p1a; p0b = p1b; p1a = n0; p1b = n1;
    }

    // bf16-rounded logits; invalid lanes -> -1e30 sentinel (exp -> 0)
    const float bv = valid ? bias[ocol] : 0.f;
    short sb[4][4];
    float lv[4][4];
    #pragma unroll
    for (int r = 0; r < 4; r++) {
        sb[0][r] = f2bf(valid ? acc0[r] + bv : -1e30f);
        sb[1][r] = f2bf(valid ? acc1[r] + bv : -1e30f);
        sb[2][r] = f2bf(valid ? acc2[r] + bv : -1e30f);
        sb[3][r] = f2bf(valid ? acc3[r] + bv : -1e30f);
        lv[0][r] = bf2f(sb[0][r]); lv[1][r] = bf2f(sb[1][r]);
        lv[2][r] = bf2f(sb[2][r]); lv[3][r] = bf2f(sb[3][r]);
    }
    if (valid) {
        #pragma unroll
        for (int q = 0; q < 4; q++)
            #pragma unroll
            for (int r = 0; r < 4; r++)
                Cb[(size_t)(q*16 + g*4 + r) * VOCAB + ocol] = sb[q][r];
    }

    #pragma unroll
    for (int q = 0; q < 4; q++) {
        #pragma unroll
        for (int r = 0; r < 4; r++) {
            float m = lv[q][r];
            m = fmaxf(m, __shfl_xor(m, 1));
            m = fmaxf(m, __shfl_xor(m, 2));
            m = fmaxf(m, __shfl_xor(m, 4));
            m = fmaxf(m, __shfl_xor(m, 8));
            if (l15 == 0) smax[wv][q*16 + g*4 + r] = m;
        }
    }
    __syncthreads();
    if (t < 64) {
        float m = smax[0][t];
        #pragma unroll
        for (int w = 1; w < 8; w++) m = fmaxf(m, smax[w][t]);
        smax[0][t] = m;
    }
    __syncthreads();
    #pragma unroll
    for (int q = 0; q < 4; q++) {
        #pragma unroll
        for (int r = 0; r < 4; r++) {
            const int row = q*16 + g*4 + r;
            float e = __expf(lv[q][r] - smax[0][row]);
            e += __shfl_xor(e, 1);
            e += __shfl_xor(e, 2);
            e += __shfl_xor(e, 4);
            e += __shfl_xor(e, 8);
            if (l15 == 0) ssum[wv][row] = e;
        }
    }
    __syncthreads();
    if (t < 64) {
        float s = 0.f;
        #pragma unroll
        for (int w = 0; w < 8; w++) s += ssum[w][t];
        bstat[((size_t)t * NOB2 + blockIdx.x) * 2 + 0] = smax[0][t];
        bstat[((size_t)t * NOB2 + blockIdx.x) * 2 + 1] = s;
    }
}

// ---------------- reduce per-block stats -> per-row (max, sum) ----------------
__global__ __launch_bounds__(256) void k_statred(const float* __restrict__ bstat, float* __restrict__ stat)
{
    const int b = blockIdx.x, t = threadIdx.x;
    const float* pr = bstat + (size_t)b * NOB2 * 2;
    __shared__ float red[8];
    float m = -1e30f;
    for (int i = t; i < NOB2; i += 256) m = fmaxf(m, pr[i*2]);
    #pragma unroll
    for (int off = 32; off; off >>= 1) m = fmaxf(m, __shfl_xor(m, off));
    if ((t & 63) == 0) red[t >> 6] = m;
    __syncthreads();
    m = fmaxf(fmaxf(red[0], red[1]), fmaxf(red[2], red[3]));
    __syncthreads();
    float s = 0.f;
    for (int i = t; i < NOB2; i += 256) s += pr[i*2+1] * __expf(pr[i*2] - m);
    #pragma unroll
    for (int off = 32; off; off >>= 1) s += __shfl_xor(s, off);
    if ((t & 63) == 0) red[(t >> 6) + 4] = s;
    __syncthreads();
    if (t == 0) { stat[b*2] = m; stat[b*2+1] = red[4]+red[5]+red[6]+red[7]; }
}

// ---------------- final_dist = 0.5*softmax(bf16 logits) ++ extra_zeros, + fused scatter ----------------
// Fully OVERWRITES out (replay-safe). Scatter contributions accumulated per-block in LDS.
// grid (25, 64), 256 thr, 8 elems/thread.
__global__ __launch_bounds__(256) void k_final(
    const short* __restrict__ Lb, const float* __restrict__ stat,
    const float* __restrict__ ez, const int* __restrict__ idx,
    const float* __restrict__ attn, float* __restrict__ out)
{
    __shared__ float sadd[2048];
    const int b = blockIdx.y, t = threadIdx.x;
    const int base = blockIdx.x * 2048;
    #pragma unroll
    for (int i = 0; i < 8; i++) sadd[t + i * 256] = 0.f;
    __syncthreads();
    for (int j = t; j < NSRC; j += 256) {
        const int v = idx[(size_t)b * NSRC + j];
        const int loc = v - base;
        if ((unsigned)loc < 2048u)
            atomicAdd(&sadd[loc], 0.5f * attn[(size_t)b * NSRC + j]);
    }
    __syncthreads();

    const float m = stat[b * 2];
    const float inv = 0.5f / stat[b * 2 + 1];
    const int v0 = base + t * 8;
    if (v0 >= VEXT) return;
    float* op = out + (size_t)b * VEXT + v0;
    const float* sp = &sadd[t * 8];
    if (v0 + 8 <= VOCAB) {
        bf16x8 x = *(const bf16x8*)&Lb[(size_t)b * VOCAB + v0];
        float2 r0 = make_float2(__expf(bf2f(x[0]) - m) * inv + sp[0], __expf(bf2f(x[1]) - m) * inv + sp[1]);
        float2 r1 = make_float2(__expf(bf2f(x[2]) - m) * inv + sp[2], __expf(bf2f(x[3]) - m) * inv + sp[3]);
        float2 r2 = make_float2(__expf(bf2f(x[4]) - m) * inv + sp[4], __expf(bf2f(x[5]) - m) * inv + sp[5]);
        float2 r3 = make_float2(__expf(bf2f(x[6]) - m) * inv + sp[6], __expf(bf2f(x[7]) - m) * inv + sp[7]);
        *(float2*)(op)     = r0;
        *(float2*)(op + 2) = r1;
        *(float2*)(op + 4) = r2;
        *(float2*)(op + 6) = r3;
    } else {
        #pragma unroll
        for (int e = 0; e < 8; e++) {
            const int v = v0 + e;
            if (v >= VEXT) break;
            float r;
            if (v < VOCAB) r = __expf(bf2f(Lb[(size_t)b * VOCAB + v]) - m) * inv;
            else           r = ez[(size_t)b * OOV + (v - VOCAB)];
            op[e] = r + sp[e];
        }
    }
}

extern "C" void kernel_launch(void* const* d_in, const int* in_sizes, int n_in,
                              void* d_out, int out_size, void* d_ws, size_t ws_size,
                              hipStream_t stream)
{
    (void)in_sizes; (void)n_in; (void)out_size; (void)ws_size;
    const int*   y     = (const int*)  d_in[0];
    const float* st1   = (const float*)d_in[1];
    const float* enc   = (const float*)d_in[2];
    const float* encM  = (const float*)d_in[3];
    const float* ct1   = (const float*)d_in[4];
    const float* ez    = (const float*)d_in[5];
    const int*   ebev  = (const int*)  d_in[6];
    const float* qmem  = (const float*)d_in[7];
    const float* qmask = (const float*)d_in[8];
    const float* emb   = (const float*)d_in[9];
    const float* xw    = (const float*)d_in[10];
    const float* xb    = (const float*)d_in[11];
    const float* wih   = (const float*)d_in[12];
    const float* whh   = (const float*)d_in[13];
    const float* bih   = (const float*)d_in[14];
    const float* bhh   = (const float*)d_in[15];
    const float* rqw   = (const float*)d_in[16];
    const float* rsw   = (const float*)d_in[17];
    const float* o1w   = (const float*)d_in[18];
    const float* o1b   = (const float*)d_in[19];
    const float* o2w   = (const float*)d_in[20];
    const float* o2b   = (const float*)d_in[21];

    float* ws  = (float*)d_ws;
    float* out = (float*)d_out;

    // region A (transient; o1p overlays it after the attn passes are done; then bf16
    // logits overwrite it after tobf16 has consumed o1p — all stream-ordered)
    constexpr size_t WS_PART = 0;         // 64*16*514 = 526336
    constexpr size_t WS_EN   = 526336;    // 32768
    constexpr size_t WS_H1   = 559104;    // 32768
    constexpr size_t WS_CTX1 = 591872;    // 32768 (ends 624640)
    constexpr size_t WS_O1P8 = 0;         // overlay: 8*64*512 = 262144, live o1gemm..tobf16
    constexpr size_t WS_LOG  = 0;         // bf16 logits: 1.6M float slots, written at out2
    // region P (persistent, packed with liveness overlays)
    constexpr size_t WS_GIP  = 3200000;   // 4*64*1536 (both GRU steps)
    constexpr size_t WS_GHP  = 3593216;   // 4*64*1536
    constexpr size_t WS_UP   = 3986432;   // 8*64*512 = 262144 (live u-gemm..attn)
    constexpr size_t WS_XP   = 3986432;   // overlay: 8*64*512, live x0gemm..gi-gemm (before UP)
    constexpr size_t WS_ABF  = 4248576 - 8192;  // 16384 float slots = 4240384, live tobf16..out2
    constexpr size_t WS_CAT2 = 4248576;   // 64*1024
    constexpr size_t WS_BSTAT= 4314112;   // 64*391*2 = 50048
    constexpr size_t WS_STAT = 4364160;   // 128 (ends 4364288)

    constexpr size_t OUT_ST = 3203200, OUT_CT = 3235968, OUT_ATTN = 3268736;

    float* part = ws + WS_PART;
    float* en   = ws + WS_EN;
    float* h1   = ws + WS_H1;
    float* ctx1 = ws + WS_CTX1;
    short* logi = (short*)(ws + WS_LOG);
    float* gip  = ws + WS_GIP;
    float* ghp  = ws + WS_GHP;
    float* up   = ws + WS_UP;
    float* xp   = ws + WS_XP;
    float* o1p  = ws + WS_O1P8;
    float* cat2 = ws + WS_CAT2;
    float* bstat= ws + WS_BSTAT;
    float* stat = ws + WS_STAT;
    short* abf  = (short*)(ws + WS_ABF);

    // 1. x = [c_t_1, emb[y]] @ x_ctx_w.T + b   (fused gather, K=1024, k-split 8)
    k_gemm_x0<<<dim3(16,8), 256, 0, stream>>>(y, ct1, emb, xw, xb, xp);
    // 2. gi = x@wih.T+bih (xp = 8 slices) ; gh = h0@whh.T+bhh   (z=2)
    k_gemm_small<true><<<dim3(48,4,2), 256, 0, stream>>>(xp, wih, bih, gip, 8,
                                                         st1, whh, bhh, ghp, 0, 512, 1536);
    // 3. h1 = GRU1 (fused); u1 = h1 @ readq_w   (k-split 8)
    k_gemm_gru<8><<<dim3(16,8), 256, 0, stream>>>(gip, ghp, st1, rqw, up, h1, nullptr);
    // 4/5. attention over query_memory -> ctx1
    k_attn_pass<<<dim3(16,64), 256, 0, stream>>>(qmem, up, qmask, en, part);
    k_attn_combine<<<dim3(64,4), 128, 0, stream>>>(part, en, qmask, ctx1, nullptr, nullptr);
    // 6. gi2 = ctx1@wih.T+bih ; gh2 = h1@whh.T+bhh
    k_gemm_small<true><<<dim3(48,4,2), 256, 0, stream>>>(ctx1, wih, bih, gip, 0,
                                                         h1, whh, bhh, ghp, 0, 512, 1536);
    // 7. h2 = GRU2 (fused, writes s_t + cat2 left); u2 = h2 @ readsrc_w
    k_gemm_gru<8><<<dim3(16,8), 256, 0, stream>>>(gip, ghp, h1, rsw, up, out + OUT_ST, cat2);
    // 8/9. attention over encoder_outputs -> c_t, attn_dist, cat2 right half
    k_attn_pass<<<dim3(16,64), 256, 0, stream>>>(enc, up, encM, en, part);
    k_attn_combine<<<dim3(64,4), 128, 0, stream>>>(part, en, encM, out + OUT_CT, cat2 + 512, out + OUT_ATTN);
    // 10. o1 = cat2 @ out1_w.T + b  (K=1024, k-split 8) -> 8 partial slices (region A)
    k_gemm_small<true><<<dim3(16,8,1), 256, 0, stream>>>(cat2, o1w, o1b, o1p, 0,
                                                         nullptr, nullptr, nullptr, nullptr, 0, 1024, 512);
    // 11. sum 8 o1 partials -> bf16 (64 KB broadcast source for out2 — R9 lesson)
    k_tobf16<<<128, 256, 0, stream>>>(o1p, abf);
    // 12. logits (bf16) + per-block softmax stats (R10 form — no batch split, R11 lesson)
    k_out2_mfma<<<NOB2, 512, 0, stream>>>(abf, o2w, o2b, logi, bstat);
    // 13. fold block stats -> per-row (M, S)
    k_statred<<<64, 256, 0, stream>>>(bstat, stat);
    // 14. final_dist = 0.5*softmax ++ extra_zeros, + LDS-fused scatter (overwrite; replay-safe)
    k_final<<<dim3(25,64), 256, 0, stream>>>(logi, stat, ez, ebev, out + OUT_ATTN, out);
}

// Round 13
// 147.952 us; speedup vs baseline: 1.1380x; 1.0092x over previous
//
#include <hip/hip_runtime.h>

#define BATCH 64
#define RNN   512
#define VOCAB 50000
#define OOV   50
#define VEXT  50050
#define NSRC  512
#define NOB2  391   // out2 blocks

typedef short bf16x8 __attribute__((ext_vector_type(8)));
typedef float f32x4  __attribute__((ext_vector_type(4)));

__device__ __forceinline__ float sigmoidf_(float x) { return 1.f / (1.f + __expf(-x)); }

__device__ __forceinline__ float gru_one(float ir, float iz, float inn,
                                         float hr, float hz, float hn, float h)
{
    const float r = sigmoidf_(ir + hr);
    const float z = sigmoidf_(iz + hz);
    const float n = tanhf(inn + r * hn);
    return (1.f - z) * n + z * h;
}

__device__ __forceinline__ short f2bf(float x) {
    unsigned u = __builtin_bit_cast(unsigned, x);
    unsigned r = (u + 0x7FFFu + ((u >> 16) & 1u)) >> 16;
    return (short)r;
}
__device__ __forceinline__ float bf2f(short s) {
    unsigned u = ((unsigned)(unsigned short)s) << 16;
    return __builtin_bit_cast(float, u);
}

// ---------------- small GEMM: C[b,o] = sum_k A[b,k] * W(o,k) (+bias) ----------------
// WT=true : W is (O,K) row-major (PyTorch Linear layout, x@W.T)
// grid = (O/32, KSPLIT, nz), kchunk = K/gridDim.y. Writes PARTIALS: C + blockIdx.y*64*O.
// asum = slice COUNT: A is asum partial slices [asum][64][K] summed while staging (0/1 = plain).
// FAILED-EXPERIMENT LOG (do not retry): register-prefetch (R4: s_t absmax 1.9e-2);
// per-block __threadfence completion fusion (R7: 3.8x, L2-writeback serialization);
// scatter-into-output accumulate (R8: replay-idempotence); consumer-side o1p f32
// staging in out2 (R9: 391x512KB re-read, +35us); out2 batch-split (R11: +15.5us,
// XCD round-robin duplicates the W2 stream).
template<bool WT>
__global__ __launch_bounds__(256) void k_gemm_small(
    const float* __restrict__ A0, const float* __restrict__ W0,
    const float* __restrict__ bias0, float* __restrict__ C0, int asum0,
    const float* __restrict__ A1, const float* __restrict__ W1,
    const float* __restrict__ bias1, float* __restrict__ C1, int asum1,
    int K, int O)
{
    const float* A = A0; const float* W = W0; const float* bias = bias0;
    float* C = C0; int asum = asum0;
    if (blockIdx.z == 1) { A = A1; W = W1; bias = bias1; C = C1; asum = asum1; }

    __shared__ float As[32 * 64];   // [k][b]
    __shared__ float Ws[32 * 32];   // [k][o]
    const int t  = threadIdx.x;
    const int tx = t & 15, ty = t >> 4;
    const int o0 = blockIdx.x * 32;
    const int kchunk = K / gridDim.y;
    const int kbeg = blockIdx.y * kchunk;
    const int kend = kbeg + kchunk;
    float acc[4][2] = {};
    const int ab  = t >> 2;         // 0..63
    const int akq = (t & 3) * 4;    // 0,4,8,12

    for (int k0 = kbeg; k0 < kend; k0 += 32) {
        {
            const float* Ap = &A[(size_t)ab * K + k0 + akq];
            float4 v0 = *(const float4*)Ap;
            float4 v1 = *(const float4*)(Ap + 16);
            for (int s = 1; s < asum; s++) {
                const float* Aps = Ap + (size_t)s * 64 * K;
                float4 w0 = *(const float4*)Aps;
                float4 w1 = *(const float4*)(Aps + 16);
                v0.x += w0.x; v0.y += w0.y; v0.z += w0.z; v0.w += w0.w;
                v1.x += w1.x; v1.y += w1.y; v1.z += w1.z; v1.w += w1.w;
            }
            As[(akq+0)*64+ab]=v0.x; As[(akq+1)*64+ab]=v0.y; As[(akq+2)*64+ab]=v0.z; As[(akq+3)*64+ab]=v0.w;
            As[(akq+16)*64+ab]=v1.x; As[(akq+17)*64+ab]=v1.y; As[(akq+18)*64+ab]=v1.z; As[(akq+19)*64+ab]=v1.w;
        }
        if (WT) {
            const int o  = t >> 3;          // 0..31
            const int kq = (t & 7) * 4;     // 0..28
            float4 v = *(const float4*)&W[(size_t)(o0 + o) * K + k0 + kq];
            Ws[(kq+0)*32+o]=v.x; Ws[(kq+1)*32+o]=v.y; Ws[(kq+2)*32+o]=v.z; Ws[(kq+3)*32+o]=v.w;
        } else {
            const int kk = t >> 3;          // 0..31
            const int oq = (t & 7) * 4;
            *(float4*)&Ws[kk*32 + oq] = *(const float4*)&W[(size_t)(k0 + kk) * O + o0 + oq];
        }
        __syncthreads();
        #pragma unroll
        for (int kk = 0; kk < 32; kk++) {
            float4 a4 = *(const float4*)&As[kk*64 + ty*4];
            float2 w2 = *(const float2*)&Ws[kk*32 + tx*2];
            acc[0][0] = fmaf(a4.x, w2.x, acc[0][0]); acc[0][1] = fmaf(a4.x, w2.y, acc[0][1]);
            acc[1][0] = fmaf(a4.y, w2.x, acc[1][0]); acc[1][1] = fmaf(a4.y, w2.y, acc[1][1]);
            acc[2][0] = fmaf(a4.z, w2.x, acc[2][0]); acc[2][1] = fmaf(a4.z, w2.y, acc[2][1]);
            acc[3][0] = fmaf(a4.w, w2.x, acc[3][0]); acc[3][1] = fmaf(a4.w, w2.y, acc[3][1]);
        }
        __syncthreads();
    }
    const int o = o0 + tx*2;
    float b0v = 0.f, b1v = 0.f;
    if (bias && blockIdx.y == 0) { b0v = bias[o]; b1v = bias[o+1]; }
    float* Cp = C + (size_t)blockIdx.y * 64 * O;
    #pragma unroll
    for (int j = 0; j < 4; j++) {
        const int bb = ty*4 + j;
        Cp[(size_t)bb*O + o]     = acc[j][0] + b0v;
        Cp[(size_t)bb*O + o + 1] = acc[j][1] + b1v;
    }
}

// ---------------- GEMM with fused x0 gather: x = [c_t_1, emb[y]] @ W.T + b ----------------
// K=1024, O=512, W (O,K) row-major, grid (16, KSPLIT), partials to C + y*64*512.
__global__ __launch_bounds__(256) void k_gemm_x0(
    const int* __restrict__ yidx, const float* __restrict__ ct1, const float* __restrict__ emb,
    const float* __restrict__ W, const float* __restrict__ bias, float* __restrict__ C)
{
    __shared__ float As[32 * 64];
    __shared__ float Ws[32 * 32];
    const int t  = threadIdx.x;
    const int tx = t & 15, ty = t >> 4;
    const int o0 = blockIdx.x * 32;
    const int kchunk = 1024 / gridDim.y;
    const int kbeg = blockIdx.y * kchunk;
    const int kend = kbeg + kchunk;
    float acc[4][2] = {};
    const int ab  = t >> 2;
    const int akq = (t & 3) * 4;
    const int erow = yidx[ab];

    for (int k0 = kbeg; k0 < kend; k0 += 32) {
        {
            // tile [k0,k0+32) lies entirely in one half (512 % 32 == 0)
            const float* src = (k0 < 512) ? (ct1 + (size_t)ab * 512 + k0)
                                          : (emb + (size_t)erow * 512 + (k0 - 512));
            float4 v0 = *(const float4*)(src + akq);
            float4 v1 = *(const float4*)(src + akq + 16);
            As[(akq+0)*64+ab]=v0.x; As[(akq+1)*64+ab]=v0.y; As[(akq+2)*64+ab]=v0.z; As[(akq+3)*64+ab]=v0.w;
            As[(akq+16)*64+ab]=v1.x; As[(akq+17)*64+ab]=v1.y; As[(akq+18)*64+ab]=v1.z; As[(akq+19)*64+ab]=v1.w;
        }
        {
            const int o  = t >> 3;
            const int kq = (t & 7) * 4;
            float4 v = *(const float4*)&W[(size_t)(o0 + o) * 1024 + k0 + kq];
            Ws[(kq+0)*32+o]=v.x; Ws[(kq+1)*32+o]=v.y; Ws[(kq+2)*32+o]=v.z; Ws[(kq+3)*32+o]=v.w;
        }
        __syncthreads();
        #pragma unroll
        for (int kk = 0; kk < 32; kk++) {
            float4 a4 = *(const float4*)&As[kk*64 + ty*4];
            float2 w2 = *(const float2*)&Ws[kk*32 + tx*2];
            acc[0][0] = fmaf(a4.x, w2.x, acc[0][0]); acc[0][1] = fmaf(a4.x, w2.y, acc[0][1]);
            acc[1][0] = fmaf(a4.y, w2.x, acc[1][0]); acc[1][1] = fmaf(a4.y, w2.y, acc[1][1]);
            acc[2][0] = fmaf(a4.z, w2.x, acc[2][0]); acc[2][1] = fmaf(a4.z, w2.y, acc[2][1]);
            acc[3][0] = fmaf(a4.w, w2.x, acc[3][0]); acc[3][1] = fmaf(a4.w, w2.y, acc[3][1]);
        }
        __syncthreads();
    }
    const int o = o0 + tx*2;
    float b0v = 0.f, b1v = 0.f;
    if (blockIdx.y == 0) { b0v = bias[o]; b1v = bias[o+1]; }
    float* Cp = C + (size_t)blockIdx.y * 64 * 512;
    #pragma unroll
    for (int j = 0; j < 4; j++) {
        const int bb = ty*4 + j;
        Cp[(size_t)bb*512 + o]     = acc[j][0] + b0v;
        Cp[(size_t)bb*512 + o + 1] = acc[j][1] + b1v;
    }
}

// ---------------- GEMM with fused GRU: u = GRU(gi,gh,hprev) @ W ----------------
// gi/gh are 4 k-split partial slices [4][64][1536]. W (K,O)=(512,512) row-major (x@W).
// grid (16, KS), 256 thr. Partials to C + y*64*512. Block x==0 also writes h (+cat).
template<int KS>
__global__ __launch_bounds__(256) void k_gemm_gru(
    const float* __restrict__ gi, const float* __restrict__ gh,
    const float* __restrict__ hprev, const float* __restrict__ W,
    float* __restrict__ C, float* __restrict__ hout, float* __restrict__ cat_out)
{
    __shared__ float As[32 * 64];
    __shared__ float Ws[32 * 32];
    const int t  = threadIdx.x;
    const int tx = t & 15, ty = t >> 4;
    const int o0 = blockIdx.x * 32;
    const int kchunk = 512 / KS;
    const int kbeg = blockIdx.y * kchunk;
    const int kend = kbeg + kchunk;
    float acc[4][2] = {};
    const int ab  = t >> 2;
    const int akq = (t & 3) * 4;

    for (int k0 = kbeg; k0 < kend; k0 += 32) {
        #pragma unroll
        for (int half = 0; half < 2; half++) {
            const int d = k0 + akq + half * 16;
            float irv[4] = {0,0,0,0}, izv[4] = {0,0,0,0}, inv_[4] = {0,0,0,0};
            float hrv[4] = {0,0,0,0}, hzv[4] = {0,0,0,0}, hnv[4] = {0,0,0,0};
            #pragma unroll
            for (int s = 0; s < 4; s++) {
                const float* gp = gi + (size_t)s * BATCH * 1536 + (size_t)ab * 1536 + d;
                const float* hp = gh + (size_t)s * BATCH * 1536 + (size_t)ab * 1536 + d;
                float4 a0 = *(const float4*)(gp);
                float4 a1 = *(const float4*)(gp + 512);
                float4 a2 = *(const float4*)(gp + 1024);
                float4 b0 = *(const float4*)(hp);
                float4 b1 = *(const float4*)(hp + 512);
                float4 b2 = *(const float4*)(hp + 1024);
                irv[0]+=a0.x; irv[1]+=a0.y; irv[2]+=a0.z; irv[3]+=a0.w;
                izv[0]+=a1.x; izv[1]+=a1.y; izv[2]+=a1.z; izv[3]+=a1.w;
                inv_[0]+=a2.x; inv_[1]+=a2.y; inv_[2]+=a2.z; inv_[3]+=a2.w;
                hrv[0]+=b0.x; hrv[1]+=b0.y; hrv[2]+=b0.z; hrv[3]+=b0.w;
                hzv[0]+=b1.x; hzv[1]+=b1.y; hzv[2]+=b1.z; hzv[3]+=b1.w;
                hnv[0]+=b2.x; hnv[1]+=b2.y; hnv[2]+=b2.z; hnv[3]+=b2.w;
            }
            const float4 hq = *(const float4*)(hprev + (size_t)ab * 512 + d);
            float o0v = gru_one(irv[0], izv[0], inv_[0], hrv[0], hzv[0], hnv[0], hq.x);
            float o1v = gru_one(irv[1], izv[1], inv_[1], hrv[1], hzv[1], hnv[1], hq.y);
            float o2v = gru_one(irv[2], izv[2], inv_[2], hrv[2], hzv[2], hnv[2], hq.z);
            float o3v = gru_one(irv[3], izv[3], inv_[3], hrv[3], hzv[3], hnv[3], hq.w);
            const int kk = akq + half * 16;
            As[(kk+0)*64+ab] = o0v; As[(kk+1)*64+ab] = o1v;
            As[(kk+2)*64+ab] = o2v; As[(kk+3)*64+ab] = o3v;
            if (blockIdx.x == 0) {
                float4 ov = make_float4(o0v, o1v, o2v, o3v);
                *(float4*)&hout[(size_t)ab * 512 + d] = ov;
                if (cat_out) *(float4*)&cat_out[(size_t)ab * 1024 + d] = ov;
            }
        }
        {
            const int kk = t >> 3;
            const int oq = (t & 7) * 4;
            *(float4*)&Ws[kk*32 + oq] = *(const float4*)&W[(size_t)(k0 + kk) * 512 + o0 + oq];
        }
        __syncthreads();
        #pragma unroll
        for (int kk = 0; kk < 32; kk++) {
            float4 a4 = *(const float4*)&As[kk*64 + ty*4];
            float2 w2 = *(const float2*)&Ws[kk*32 + tx*2];
            acc[0][0] = fmaf(a4.x, w2.x, acc[0][0]); acc[0][1] = fmaf(a4.x, w2.y, acc[0][1]);
            acc[1][0] = fmaf(a4.y, w2.x, acc[1][0]); acc[1][1] = fmaf(a4.y, w2.y, acc[1][1]);
            acc[2][0] = fmaf(a4.z, w2.x, acc[2][0]); acc[2][1] = fmaf(a4.z, w2.y, acc[2][1]);
            acc[3][0] = fmaf(a4.w, w2.x, acc[3][0]); acc[3][1] = fmaf(a4.w, w2.y, acc[3][1]);
        }
        __syncthreads();
    }
    const int o = o0 + tx*2;
    float* Cp = C + (size_t)blockIdx.y * 64 * 512;
    #pragma unroll
    for (int j = 0; j < 4; j++) {
        const int bb = ty*4 + j;
        Cp[(size_t)bb*512 + o]     = acc[j][0];
        Cp[(size_t)bb*512 + o + 1] = acc[j][1];
    }
}

// ---------------- fused attention pass ----------------
__global__ __launch_bounds__(256) void k_attn_pass(
    const float* __restrict__ KV, const float* __restrict__ Upart,
    const float* __restrict__ mask, float* __restrict__ en, float* __restrict__ part)
{
    const int b = blockIdx.y;
    const int chunk = blockIdx.x;
    const int t = threadIdx.x;
    const int lane = t & 63;
    const int wv = t >> 6;
    const float* KVb = KV + (size_t)b * NSRC * RNN;

    const int r0 = chunk * 32 + wv * 8;

    float4 x[8][2];
    float mk[8];
    #pragma unroll
    for (int i = 0; i < 8; i++) {
        const float* rp = KVb + (size_t)(r0 + i) * RNN + lane * 8;
        x[i][0] = *(const float4*)rp;
        x[i][1] = *(const float4*)(rp + 4);
    }
    #pragma unroll
    for (int i = 0; i < 8; i++) mk[i] = mask[(size_t)b * NSRC + r0 + i];

    float4 u0, u1;
    {
        const float* up = Upart + (size_t)b * RNN + lane * 8;
        u0 = *(const float4*)up; u1 = *(const float4*)(up + 4);
        #pragma unroll
        for (int s = 1; s < 8; s++) {
            const float* ups = up + (size_t)s * BATCH * RNN;
            float4 a = *(const float4*)ups; float4 c = *(const float4*)(ups + 4);
            u0.x += a.x; u0.y += a.y; u0.z += a.z; u0.w += a.w;
            u1.x += c.x; u1.y += c.y; u1.z += c.z; u1.w += c.w;
        }
    }

    float m_run = -1e30f, s_run = 0.f;
    float acc[8] = {0,0,0,0,0,0,0,0};
    #pragma unroll
    for (int i = 0; i < 8; i++) {
        const int n = r0 + i;
        float d = x[i][0].x*u0.x + x[i][0].y*u0.y + x[i][0].z*u0.z + x[i][0].w*u0.w
                + x[i][1].x*u1.x + x[i][1].y*u1.y + x[i][1].z*u1.z + x[i][1].w*u1.w;
        #pragma unroll
        for (int off = 32; off; off >>= 1) d += __shfl_xor(d, off);
        const float s = d * mk[i] * mk[i];      // ref masks e then en
        if (lane == 0) en[(size_t)b * NSRC + n] = s;
        const float mnew = fmaxf(m_run, s);
        const float sc = __expf(m_run - mnew);
        const float w  = __expf(s - mnew) * mk[i];
        s_run = s_run * sc + w;
        acc[0] = acc[0]*sc + w*x[i][0].x; acc[1] = acc[1]*sc + w*x[i][0].y;
        acc[2] = acc[2]*sc + w*x[i][0].z; acc[3] = acc[3]*sc + w*x[i][0].w;
        acc[4] = acc[4]*sc + w*x[i][1].x; acc[5] = acc[5]*sc + w*x[i][1].y;
        acc[6] = acc[6]*sc + w*x[i][1].z; acc[7] = acc[7]*sc + w*x[i][1].w;
        m_run = mnew;
    }
    __shared__ float sm[4], ss[4];
    __shared__ float sacc[4][512];
    *(float4*)&sacc[wv][lane*8]     = make_float4(acc[0], acc[1], acc[2], acc[3]);
    *(float4*)&sacc[wv][lane*8 + 4] = make_float4(acc[4], acc[5], acc[6], acc[7]);
    if (lane == 0) { sm[wv] = m_run; ss[wv] = s_run; }
    __syncthreads();
    const float M = fmaxf(fmaxf(sm[0], sm[1]), fmaxf(sm[2], sm[3]));
    const float e0 = __expf(sm[0]-M), e1 = __expf(sm[1]-M), e2 = __expf(sm[2]-M), e3 = __expf(sm[3]-M);
    const float S = ss[0]*e0 + ss[1]*e1 + ss[2]*e2 + ss[3]*e3;
    float* pp = part + (size_t)(b * 16 + chunk) * 514;
    const int c = t;
    pp[2 + c]       = sacc[0][c]*e0 + sacc[1][c]*e1 + sacc[2][c]*e2 + sacc[3][c]*e3;
    pp[2 + c + 256] = sacc[0][c+256]*e0 + sacc[1][c+256]*e1 + sacc[2][c+256]*e2 + sacc[3][c+256]*e3;
    if (t == 0) { pp[0] = M; pp[1] = S; }
}

// ---------------- combine chunk partials -> ctx (+ optional cat-half + attn weights) ----------------
// grid (64 batches, 4 d-chunks), 128 threads.
__global__ __launch_bounds__(128) void k_attn_combine(
    const float* __restrict__ part, const float* __restrict__ en,
    const float* __restrict__ mask, float* __restrict__ ctx,
    float* __restrict__ ctx2, float* __restrict__ attn_out)
{
    const int b = blockIdx.x, z = blockIdx.y, t = threadIdx.x;
    const float* pb = part + (size_t)b * 16 * 514;
    float M = -1e30f;
    #pragma unroll
    for (int c = 0; c < 16; c++) M = fmaxf(M, pb[c * 514]);
    float e[16]; float S = 0.f;
    #pragma unroll
    for (int c = 0; c < 16; c++) { e[c] = __expf(pb[c * 514] - M); S += pb[c * 514 + 1] * e[c]; }
    const float inv = 1.f / (S + 1e-10f);
    const int d = z * 128 + t;
    float a = 0.f;
    #pragma unroll
    for (int c = 0; c < 16; c++) a += pb[c * 514 + 2 + d] * e[c];
    const float val = a * inv;
    ctx[(size_t)b * 512 + d] = val;
    if (ctx2) ctx2[(size_t)b * 1024 + d] = val;
    if (attn_out)
        attn_out[(size_t)b * NSRC + d] = __expf(en[(size_t)b * NSRC + d] - M) * mask[(size_t)b * NSRC + d] * inv;
}

// ---------------- o1 partial-sum (8 slices) + f32->bf16 ----------------
__global__ void k_tobf16(const float* __restrict__ in, short* __restrict__ outp)
{
    const int i = blockIdx.x * 256 + threadIdx.x;  // 32768 total
    float v = 0.f;
    #pragma unroll
    for (int s = 0; s < 8; s++) v += in[s * 32768 + i];
    outp[i] = f2bf(v);
}

// ---------------- out2: logits = A(64x512,bf16) @ W2(50000x512)^T + b2, bf16 MFMA ----------------
// R10-proven form: 391 blocks x 512 thr, all resident (2/CU, 64 KB LDS); single pass
// over W2 (no batch split — R11 lesson). bf16 logits; per-block stats -> bstat.
__global__ __launch_bounds__(512, 4) void k_out2_mfma(
    const short* __restrict__ Abf, const float* __restrict__ W2,
    const float* __restrict__ bias, short* __restrict__ Cb, float* __restrict__ bstat)
{
    __shared__ alignas(16) short As[64 * 512];    // 64 KB
    __shared__ float smax[8][64];
    __shared__ float ssum[8][64];
    const int t = threadIdx.x;
    const int lane = t & 63, wv = t >> 6;

    {
        char* Asb = (char*)As;
        const char* Ab = (const char*)Abf;
        #pragma unroll
        for (int it = 0; it < 8; ++it) {
            const int off = (it * 512 + t) * 16;
            const int row = off >> 10;
            const int kb  = off & 1023;
            bf16x8 v = *(const bf16x8*)(Ab + off);
            *(bf16x8*)(Asb + row * 1024 + (kb ^ ((row & 7) << 4))) = v;
        }
    }
    __syncthreads();

    const int l15 = lane & 15, g = lane >> 4;
    const int goff = g * 8;
    const int obase = blockIdx.x * 128 + wv * 16;
    const int ocol = obase + l15;
    const bool valid = (ocol < VOCAB);
    const int orow = valid ? ocol : (VOCAB - 1);
    const float* wr = &W2[(size_t)orow * RNN + goff];

    const int sw = (l15 & 7) << 4;
    const char* a0b = (const char*)As + (l15     ) * 1024;
    const char* a1b = (const char*)As + (l15 + 16) * 1024;
    const char* a2b = (const char*)As + (l15 + 32) * 1024;
    const char* a3b = (const char*)As + (l15 + 48) * 1024;

    f32x4 acc0 = {0,0,0,0}, acc1 = {0,0,0,0}, acc2 = {0,0,0,0}, acc3 = {0,0,0,0};

    float4 p0a = *(const float4*)(wr);
    float4 p0b = *(const float4*)(wr + 4);
    float4 p1a = *(const float4*)(wr + 32);
    float4 p1b = *(const float4*)(wr + 36);
    #pragma unroll 4
    for (int k0 = 0; k0 < RNN; k0 += 32) {
        const int kn = (k0 + 64) & 511;
        float4 n0 = *(const float4*)(wr + kn);
        float4 n1 = *(const float4*)(wr + kn + 4);
        const int kb = ((k0 + goff) * 2) ^ sw;
        bf16x8 a0 = *(const bf16x8*)(a0b + kb);
        bf16x8 a1 = *(const bf16x8*)(a1b + kb);
        bf16x8 a2 = *(const bf16x8*)(a2b + kb);
        bf16x8 a3 = *(const bf16x8*)(a3b + kb);
        bf16x8 bf;
        bf[0]=f2bf(p0a.x); bf[1]=f2bf(p0a.y); bf[2]=f2bf(p0a.z); bf[3]=f2bf(p0a.w);
        bf[4]=f2bf(p0b.x); bf[5]=f2bf(p0b.y); bf[6]=f2bf(p0b.z); bf[7]=f2bf(p0b.w);
        acc0 = __builtin_amdgcn_mfma_f32_16x16x32_bf16(a0, bf, acc0, 0, 0, 0);
        acc1 = __builtin_amdgcn_mfma_f32_16x16x32_bf16(a1, bf, acc1, 0, 0, 0);
        acc2 = __builtin_amdgcn_mfma_f32_16x16x32_bf16(a2, bf, acc2, 0, 0, 0);
        acc3 = __builtin_amdgcn_mfma_f32_16x16x32_bf16(a3, bf, acc3, 0, 0, 0);
        p0a = p1a; p0b = p1b; p1a = n0; p1b = n1;
    }

    // bf16-rounded logits; invalid lanes -> -1e30 sentinel (exp -> 0)
    const float bv = valid ? bias[ocol] : 0.f;
    short sb[4][4];
    float lv[4][4];
    #pragma unroll
    for (int r = 0; r < 4; r++) {
        sb[0][r] = f2bf(valid ? acc0[r] + bv : -1e30f);
        sb[1][r] = f2bf(valid ? acc1[r] + bv : -1e30f);
        sb[2][r] = f2bf(valid ? acc2[r] + bv : -1e30f);
        sb[3][r] = f2bf(valid ? acc3[r] + bv : -1e30f);
        lv[0][r] = bf2f(sb[0][r]); lv[1][r] = bf2f(sb[1][r]);
        lv[2][r] = bf2f(sb[2][r]); lv[3][r] = bf2f(sb[3][r]);
    }
    if (valid) {
        #pragma unroll
        for (int q = 0; q < 4; q++)
            #pragma unroll
            for (int r = 0; r < 4; r++)
                Cb[(size_t)(q*16 + g*4 + r) * VOCAB + ocol] = sb[q][r];
    }

    #pragma unroll
    for (int q = 0; q < 4; q++) {
        #pragma unroll
        for (int r = 0; r < 4; r++) {
            float m = lv[q][r];
            m = fmaxf(m, __shfl_xor(m, 1));
            m = fmaxf(m, __shfl_xor(m, 2));
            m = fmaxf(m, __shfl_xor(m, 4));
            m = fmaxf(m, __shfl_xor(m, 8));
            if (l15 == 0) smax[wv][q*16 + g*4 + r] = m;
        }
    }
    __syncthreads();
    if (t < 64) {
        float m = smax[0][t];
        #pragma unroll
        for (int w = 1; w < 8; w++) m = fmaxf(m, smax[w][t]);
        smax[0][t] = m;
    }
    __syncthreads();
    #pragma unroll
    for (int q = 0; q < 4; q++) {
        #pragma unroll
        for (int r = 0; r < 4; r++) {
            const int row = q*16 + g*4 + r;
            float e = __expf(lv[q][r] - smax[0][row]);
            e += __shfl_xor(e, 1);
            e += __shfl_xor(e, 2);
            e += __shfl_xor(e, 4);
            e += __shfl_xor(e, 8);
            if (l15 == 0) ssum[wv][row] = e;
        }
    }
    __syncthreads();
    if (t < 64) {
        float s = 0.f;
        #pragma unroll
        for (int w = 0; w < 8; w++) s += ssum[w][t];
        bstat[((size_t)t * NOB2 + blockIdx.x) * 2 + 0] = smax[0][t];
        bstat[((size_t)t * NOB2 + blockIdx.x) * 2 + 1] = s;
    }
}

// ---------------- final_dist = 0.5*softmax(bf16 logits) ++ extra_zeros, + fused scatter ----------------
// bstat reduced in-block with the SAME stride/shuffle tree as the old k_statred
// (bitwise-identical m,s per batch). Fully OVERWRITES out (replay-safe).
// grid (25, 64), 256 thr, 8 elems/thread.
__global__ __launch_bounds__(256) void k_final(
    const short* __restrict__ Lb, const float* __restrict__ bstat,
    const float* __restrict__ ez, const int* __restrict__ idx,
    const float* __restrict__ attn, float* __restrict__ out)
{
    __shared__ float sadd[2048];
    __shared__ float red[8];
    const int b = blockIdx.y, t = threadIdx.x;
    const int base = blockIdx.x * 2048;

    // ---- inline statred (same tree as old k_statred -> identical float results) ----
    const float* pr = bstat + (size_t)b * NOB2 * 2;
    float m = -1e30f;
    for (int i = t; i < NOB2; i += 256) m = fmaxf(m, pr[i*2]);
    #pragma unroll
    for (int off = 32; off; off >>= 1) m = fmaxf(m, __shfl_xor(m, off));
    if ((t & 63) == 0) red[t >> 6] = m;
    __syncthreads();
    m = fmaxf(fmaxf(red[0], red[1]), fmaxf(red[2], red[3]));
    __syncthreads();
    float s = 0.f;
    for (int i = t; i < NOB2; i += 256) s += pr[i*2+1] * __expf(pr[i*2] - m);
    #pragma unroll
    for (int off = 32; off; off >>= 1) s += __shfl_xor(s, off);
    if ((t & 63) == 0) red[(t >> 6) + 4] = s;

    // ---- scatter accumulation into LDS (overlapped with the reduction) ----
    #pragma unroll
    for (int i = 0; i < 8; i++) sadd[t + i * 256] = 0.f;
    __syncthreads();
    s = red[4] + red[5] + red[6] + red[7];
    for (int j = t; j < NSRC; j += 256) {
        const int v = idx[(size_t)b * NSRC + j];
        const int loc = v - base;
        if ((unsigned)loc < 2048u)
            atomicAdd(&sadd[loc], 0.5f * attn[(size_t)b * NSRC + j]);
    }
    __syncthreads();

    const float inv = 0.5f / s;
    const int v0 = base + t * 8;
    if (v0 >= VEXT) return;
    float* op = out + (size_t)b * VEXT + v0;
    const float* sp = &sadd[t * 8];
    if (v0 + 8 <= VOCAB) {
        bf16x8 x = *(const bf16x8*)&Lb[(size_t)b * VOCAB + v0];
        float2 r0 = make_float2(__expf(bf2f(x[0]) - m) * inv + sp[0], __expf(bf2f(x[1]) - m) * inv + sp[1]);
        float2 r1 = make_float2(__expf(bf2f(x[2]) - m) * inv + sp[2], __expf(bf2f(x[3]) - m) * inv + sp[3]);
        float2 r2 = make_float2(__expf(bf2f(x[4]) - m) * inv + sp[4], __expf(bf2f(x[5]) - m) * inv + sp[5]);
        float2 r3 = make_float2(__expf(bf2f(x[6]) - m) * inv + sp[6], __expf(bf2f(x[7]) - m) * inv + sp[7]);
        *(float2*)(op)     = r0;
        *(float2*)(op + 2) = r1;
        *(float2*)(op + 4) = r2;
        *(float2*)(op + 6) = r3;
    } else {
        #pragma unroll
        for (int e = 0; e < 8; e++) {
            const int v = v0 + e;
            if (v >= VEXT) break;
            float r;
            if (v < VOCAB) r = __expf(bf2f(Lb[(size_t)b * VOCAB + v]) - m) * inv;
            else           r = ez[(size_t)b * OOV + (v - VOCAB)];
            op[e] = r + sp[e];
        }
    }
}

extern "C" void kernel_launch(void* const* d_in, const int* in_sizes, int n_in,
                              void* d_out, int out_size, void* d_ws, size_t ws_size,
                              hipStream_t stream)
{
    (void)in_sizes; (void)n_in; (void)out_size; (void)ws_size;
    const int*   y     = (const int*)  d_in[0];
    const float* st1   = (const float*)d_in[1];
    const float* enc   = (const float*)d_in[2];
    const float* encM  = (const float*)d_in[3];
    const float* ct1   = (const float*)d_in[4];
    const float* ez    = (const float*)d_in[5];
    const int*   ebev  = (const int*)  d_in[6];
    const float* qmem  = (const float*)d_in[7];
    const float* qmask = (const float*)d_in[8];
    const float* emb   = (const float*)d_in[9];
    const float* xw    = (const float*)d_in[10];
    const float* xb    = (const float*)d_in[11];
    const float* wih   = (const float*)d_in[12];
    const float* whh   = (const float*)d_in[13];
    const float* bih   = (const float*)d_in[14];
    const float* bhh   = (const float*)d_in[15];
    const float* rqw   = (const float*)d_in[16];
    const float* rsw   = (const float*)d_in[17];
    const float* o1w   = (const float*)d_in[18];
    const float* o1b   = (const float*)d_in[19];
    const float* o2w   = (const float*)d_in[20];
    const float* o2b   = (const float*)d_in[21];

    float* ws  = (float*)d_ws;
    float* out = (float*)d_out;

    // region A (transient; o1p overlays it after the attn passes are done; then bf16
    // logits overwrite it after tobf16 has consumed o1p — all stream-ordered)
    constexpr size_t WS_PART = 0;         // 64*16*514 = 526336
    constexpr size_t WS_EN   = 526336;    // 32768
    constexpr size_t WS_H1   = 559104;    // 32768
    constexpr size_t WS_CTX1 = 591872;    // 32768 (ends 624640)
    constexpr size_t WS_O1P8 = 0;         // overlay: 8*64*512 = 262144, live o1gemm..tobf16
    constexpr size_t WS_LOG  = 0;         // bf16 logits: 1.6M float slots, written at out2
    // region P (persistent, packed with liveness overlays)
    constexpr size_t WS_GIP  = 3200000;   // 4*64*1536 (both GRU steps)
    constexpr size_t WS_GHP  = 3593216;   // 4*64*1536
    constexpr size_t WS_UP   = 3986432;   // 8*64*512 = 262144 (live u-gemm..attn)
    constexpr size_t WS_XP   = 3986432;   // overlay: 8*64*512, live x0gemm..gi-gemm (before UP)
    constexpr size_t WS_ABF  = 4248576 - 8192;  // 16384 float slots = 4240384, live tobf16..out2
    constexpr size_t WS_CAT2 = 4248576;   // 64*1024
    constexpr size_t WS_BSTAT= 4314112;   // 64*391*2 = 50048 (ends 4364160)

    constexpr size_t OUT_ST = 3203200, OUT_CT = 3235968, OUT_ATTN = 3268736;

    float* part = ws + WS_PART;
    float* en   = ws + WS_EN;
    float* h1   = ws + WS_H1;
    float* ctx1 = ws + WS_CTX1;
    short* logi = (short*)(ws + WS_LOG);
    float* gip  = ws + WS_GIP;
    float* ghp  = ws + WS_GHP;
    float* up   = ws + WS_UP;
    float* xp   = ws + WS_XP;
    float* o1p  = ws + WS_O1P8;
    float* cat2 = ws + WS_CAT2;
    float* bstat= ws + WS_BSTAT;
    short* abf  = (short*)(ws + WS_ABF);

    // 1. x = [c_t_1, emb[y]] @ x_ctx_w.T + b   (fused gather, K=1024, k-split 8)
    k_gemm_x0<<<dim3(16,8), 256, 0, stream>>>(y, ct1, emb, xw, xb, xp);
    // 2. gi = x@wih.T+bih (xp = 8 slices) ; gh = h0@whh.T+bhh   (z=2)
    k_gemm_small<true><<<dim3(48,4,2), 256, 0, stream>>>(xp, wih, bih, gip, 8,
                                                         st1, whh, bhh, ghp, 0, 512, 1536);
    // 3. h1 = GRU1 (fused); u1 = h1 @ readq_w   (k-split 8)
    k_gemm_gru<8><<<dim3(16,8), 256, 0, stream>>>(gip, ghp, st1, rqw, up, h1, nullptr);
    // 4/5. attention over query_memory -> ctx1
    k_attn_pass<<<dim3(16,64), 256, 0, stream>>>(qmem, up, qmask, en, part);
    k_attn_combine<<<dim3(64,4), 128, 0, stream>>>(part, en, qmask, ctx1, nullptr, nullptr);
    // 6. gi2 = ctx1@wih.T+bih ; gh2 = h1@whh.T+bhh
    k_gemm_small<true><<<dim3(48,4,2), 256, 0, stream>>>(ctx1, wih, bih, gip, 0,
                                                         h1, whh, bhh, ghp, 0, 512, 1536);
    // 7. h2 = GRU2 (fused, writes s_t + cat2 left); u2 = h2 @ readsrc_w
    k_gemm_gru<8><<<dim3(16,8), 256, 0, stream>>>(gip, ghp, h1, rsw, up, out + OUT_ST, cat2);
    // 8/9. attention over encoder_outputs -> c_t, attn_dist, cat2 right half
    k_attn_pass<<<dim3(16,64), 256, 0, stream>>>(enc, up, encM, en, part);
    k_attn_combine<<<dim3(64,4), 128, 0, stream>>>(part, en, encM, out + OUT_CT, cat2 + 512, out + OUT_ATTN);
    // 10. o1 = cat2 @ out1_w.T + b  (K=1024, k-split 8) -> 8 partial slices (region A)
    k_gemm_small<true><<<dim3(16,8,1), 256, 0, stream>>>(cat2, o1w, o1b, o1p, 0,
                                                         nullptr, nullptr, nullptr, nullptr, 0, 1024, 512);
    // 11. sum 8 o1 partials -> bf16 (64 KB broadcast source for out2 — R9 lesson)
    k_tobf16<<<128, 256, 0, stream>>>(o1p, abf);
    // 12. logits (bf16) + per-block softmax stats (R10 form — no batch split, R11 lesson)
    k_out2_mfma<<<NOB2, 512, 0, stream>>>(abf, o2w, o2b, logi, bstat);
    // 13. final_dist = 0.5*softmax ++ extra_zeros, + LDS scatter + inline statred
    //     (overwrite; replay-safe; statred tree identical to the old k_statred)
    k_final<<<dim3(25,64), 256, 0, stream>>>(logi, bstat, ez, ebev, out + OUT_ATTN, out);
}